// Round 15
// baseline (479.229 us; speedup 1.0000x reference)
//
#include <hip/hip_runtime.h>
#include <hip/hip_bf16.h>

#define Bn 32
#define Dd 256
#define Tt 1024
#define Nn (Bn * Tt)   // 32768
#define Kk 8192

typedef __attribute__((ext_vector_type(8))) short bf16x8;
typedef __attribute__((ext_vector_type(4))) float f32x4;

static __device__ __forceinline__ short f2bf(float v) {
    __hip_bfloat16 h = __float2bfloat16(v);
    return *reinterpret_cast<short*>(&h);
}

// ===================== ws layout (total == proven 75927808) ====================
#define OFF_XT    0ULL            // f32 [32768][256]  32 MB
#define OFF_XBT   33554432ULL     // bf16 [32768][256] 16 MB (dead after filter -> mask reuses)
#define OFF_WBT   50331648ULL     // bf16 [8192][256]   4 MB
#define OFF_CM    54525952ULL     // f32 [32768][128]  16 MB  (chunk-min, col=2c+cp)
#define OFF_LIST  71303168ULL     // u16 [64][32768]    4 MB
#define OFF_KEYS  75497472ULL     // u64 [32768]      256 KB
#define OFF_SW2   75759616ULL     // f32 [8192]
#define OFF_CN    75792384ULL     // f32 [32768]
#define OFF_CNT   75923456ULL     // u32 [64]
#define OFF_PART  75923712ULL     // f64 [512]
#define WS_NEED   75927808ULL
#define OFF_MASK  OFF_XBT         // u64 [32768] 256 KB, aliases dead xbt

// ---- prep: x [b][d][t] -> xT f32 [n][d], xbt bf16 [n][d] ----
__global__ void k_xprep(const float* __restrict__ x, float* __restrict__ xT,
                        short* __restrict__ xbt) {
    __shared__ float tile[32][33];
    const int b = blockIdx.z, d0 = blockIdx.y * 32, t0 = blockIdx.x * 32;
    const int tx = threadIdx.x, ty = threadIdx.y;
#pragma unroll
    for (int r = 0; r < 32; r += 8)
        tile[ty + r][tx] = x[((size_t)(b * Dd + d0 + ty + r)) * Tt + t0 + tx];
    __syncthreads();
#pragma unroll
    for (int r = 0; r < 32; r += 8) {
        const size_t o = (size_t)(b * Tt + t0 + ty + r) * Dd + d0 + tx;
        const float v = tile[tx][ty + r];
        xT[o] = v;
        xbt[o] = f2bf(v);
    }
}

// ---- prep: w -> bf16 elementwise ----
__global__ void k_wbf(const float* __restrict__ w, short* __restrict__ wbt) {
    const int i = (blockIdx.x * 256 + threadIdx.x) * 4;
    const float4 v = *reinterpret_cast<const float4*>(&w[i]);
    short4 o;
    o.x = f2bf(v.x); o.y = f2bf(v.y); o.z = f2bf(v.z); o.w = f2bf(v.w);
    *reinterpret_cast<short4*>(&wbt[i]) = o;
}

// ---- numpy-pairwise-exact sum of squares (proven round 2; round-9 grid) ----
__global__ void k_sumx2_np(const float* __restrict__ x, float* __restrict__ c) {
#pragma clang fp contract(off)
    const int n = blockIdx.x * 128 + threadIdx.x;
    const int b = n >> 10, t = n & 1023;
    const float* p = x + (size_t)b * (Dd * Tt) + t;
    float h[2];
#pragma unroll
    for (int half = 0; half < 2; ++half) {
        float r[8];
#pragma unroll
        for (int j = 0; j < 8; ++j) {
            const float v = p[(size_t)(half * 128 + j) * Tt];
            r[j] = v * v;
        }
        for (int i = 8; i < 128; i += 8) {
#pragma unroll
            for (int j = 0; j < 8; ++j) {
                const float v = p[(size_t)(half * 128 + i + j) * Tt];
                const float sq = v * v;
                r[j] = r[j] + sq;
            }
        }
        h[half] = ((r[0] + r[1]) + (r[2] + r[3])) + ((r[4] + r[5]) + (r[6] + r[7]));
    }
    c[n] = h[0] + h[1];
}

__global__ void k_sumw2_np(const float* __restrict__ w, float* __restrict__ sw) {
#pragma clang fp contract(off)
    const int k = blockIdx.x * 256 + threadIdx.x;
    const float* p = w + (size_t)k * Dd;
    float h[2];
#pragma unroll
    for (int half = 0; half < 2; ++half) {
        float r[8];
#pragma unroll
        for (int j = 0; j < 8; ++j) {
            const float v = p[half * 128 + j];
            r[j] = v * v;
        }
        for (int i = 8; i < 128; i += 8) {
#pragma unroll
            for (int j = 0; j < 8; ++j) {
                const float v = p[half * 128 + i + j];
                const float sq = v * v;
                r[j] = r[j] + sq;
            }
        }
        h[half] = ((r[0] + r[1]) + (r[2] + r[3])) + ((r[4] + r[5]) + (r[6] + r[7]));
    }
    sw[k] = h[0] + h[1];
}

// ---- stage 1: bf16 MFMA filter v6 — round-8 structure, fragment-ordered LDS
// with LINEAR lane-order writes (rule #21: permutation lives in the per-lane
// GLOBAL source offset, both LDS sides bank-optimal).
// Wf 16B-unit p = (g*8+ks)*64 + l4*16 + l15 holds wbt[(128c+16g+l15)*256 + ks*32 + l4*8].
// Stage: lane e writes unit e (contiguous 1KB/wave); B-read: contiguous 1KB/wave.
__global__ void __launch_bounds__(512, 4)
k_mfma_filter(const short* __restrict__ xbt, const short* __restrict__ wbt,
              const float* __restrict__ sw2, float* __restrict__ cm) {
    __shared__ __align__(16) short Wf[32768];   // 64 KB
    const int tid = threadIdx.x;
    const int n0 = blockIdx.x * 128;
    const int cbase = blockIdx.y * 32;
    const int wid = tid >> 6, lane = tid & 63;
    const int rp = wid >> 1, cp = wid & 1;
    const int l15 = lane & 15, l4 = lane >> 4;

    bf16x8 a[2][8];
#pragma unroll
    for (int rt = 0; rt < 2; ++rt)
#pragma unroll
        for (int ks = 0; ks < 8; ++ks)
            a[rt][ks] = *reinterpret_cast<const bf16x8*>(
                &xbt[(size_t)(n0 + 32 * rp + 16 * rt + l15) * Dd + 32 * ks + 8 * l4]);

    // per-lane source offsets (bf16 units) for the inverse fragment map
    int loff[8];
#pragma unroll
    for (int m = 0; m < 8; ++m) {
        const int e = tid + 512 * m;       // LDS 16B-unit index 0..4095
        const int seg = e >> 6;            // 0..63
        const int g = seg >> 3, ks = seg & 7;
        const int ll = e & 63;
        const int fl4 = ll >> 4, fl15 = ll & 15;
        loff[m] = (16 * g + fl15) * Dd + ks * 32 + fl4 * 8;
    }

    for (int cc = 0; cc < 32; ++cc) {
        const int c = cbase + cc;
        const short* wc = wbt + (size_t)(128 * c) * Dd;
#pragma unroll
        for (int m = 0; m < 8; ++m) {
            const int e = tid + 512 * m;
            *reinterpret_cast<bf16x8*>(&Wf[e * 8]) =
                *reinterpret_cast<const bf16x8*>(&wc[loff[m]]);
        }
        __syncthreads();

        f32x4 acc[2][4];
#pragma unroll
        for (int rt = 0; rt < 2; ++rt)
#pragma unroll
            for (int ct = 0; ct < 4; ++ct) acc[rt][ct] = (f32x4)0.0f;

#pragma unroll
        for (int ks = 0; ks < 8; ++ks) {
            bf16x8 b[4];
#pragma unroll
            for (int ct = 0; ct < 4; ++ct)
                b[ct] = *reinterpret_cast<const bf16x8*>(
                    &Wf[(((4 * cp + ct) * 8 + ks) * 64 + lane) * 8]);
#pragma unroll
            for (int rt = 0; rt < 2; ++rt)
#pragma unroll
                for (int ct = 0; ct < 4; ++ct)
                    acc[rt][ct] = __builtin_amdgcn_mfma_f32_16x16x32_bf16(
                        a[rt][ks], b[ct], acc[rt][ct], 0, 0, 0);
        }
        __syncthreads();   // Wf reads done; next iteration may restage

        float swc[4];
#pragma unroll
        for (int ct = 0; ct < 4; ++ct)
            swc[ct] = sw2[128 * c + 64 * cp + 16 * ct + l15];
#pragma unroll
        for (int rt = 0; rt < 2; ++rt) {
#pragma unroll
            for (int r = 0; r < 4; ++r) {
                float mm = fmaf(-2.0f, acc[rt][0][r], swc[0]);
#pragma unroll
                for (int ct = 1; ct < 4; ++ct)
                    mm = fminf(mm, fmaf(-2.0f, acc[rt][ct][r], swc[ct]));
#pragma unroll
                for (int d = 1; d < 16; d <<= 1)
                    mm = fminf(mm, __shfl_xor(mm, d));
                if (l15 == 0) {
                    const int row = n0 + 32 * rp + 16 * rt + 4 * l4 + r;
                    cm[(size_t)row * 128 + 2 * c + cp] = mm;   // [n][128], race-free
                }
            }
        }
    }
}

// ---- mask: per-row chunk mask over 128 cm columns (round-8 proven) ----
__global__ void __launch_bounds__(256)
k_mask(const float* __restrict__ cm, const float* __restrict__ cn,
       unsigned long long* __restrict__ mask, unsigned long long* __restrict__ keys) {
    const int tid = threadIdx.x;
    const int lane = tid & 63, w = tid >> 6;
    const int grp = lane >> 4, sub = lane & 15;
    const int n0 = blockIdx.x * 256;
    for (int pass = 0; pass < 16; ++pass) {
        const int row = n0 + pass * 16 + 4 * w + grp;
        const float4 v0 = *reinterpret_cast<const float4*>(&cm[(size_t)row * 128 + 8 * sub]);
        const float4 v1 = *reinterpret_cast<const float4*>(&cm[(size_t)row * 128 + 8 * sub + 4]);
        float gmin = fminf(fminf(fminf(v0.x, v0.y), fminf(v0.z, v0.w)),
                           fminf(fminf(v1.x, v1.y), fminf(v1.z, v1.w)));
#pragma unroll
        for (int m = 1; m < 16; m <<= 1) gmin = fminf(gmin, __shfl_xor(gmin, m));
        const float margin = 7.1e-5f + 2.6e-5f * sqrtf(cn[row]);
        const float thr = gmin + margin;
        unsigned int nib = 0;
        if (fminf(v0.x, v0.y) <= thr) nib |= 1u;
        if (fminf(v0.z, v0.w) <= thr) nib |= 2u;
        if (fminf(v1.x, v1.y) <= thr) nib |= 4u;
        if (fminf(v1.z, v1.w) <= thr) nib |= 8u;
        unsigned long long mk = (unsigned long long)nib << (4 * sub);
#pragma unroll
        for (int m = 1; m < 16; m <<= 1) mk |= __shfl_xor(mk, m);
        if (sub == 0) {
            mask[row] = mk;
            keys[row] = 0xFFFFFFFFFFFFFFFFULL;
        }
    }
}

// ---- compact: per-chunk candidate list via block prefix sum (proven round 7) ----
__global__ void __launch_bounds__(1024)
k_compact(const unsigned long long* __restrict__ mask,
          unsigned int* __restrict__ cnt, unsigned short* __restrict__ lists) {
    __shared__ unsigned int sc[1024];
    const int c = blockIdx.x;
    const int t = threadIdx.x;
    const int r0 = t * 32;
    unsigned int word = 0;
#pragma unroll
    for (int j = 0; j < 32; ++j)
        word |= (unsigned int)((mask[r0 + j] >> c) & 1ULL) << j;
    const unsigned int mycnt = __popc(word);
    sc[t] = mycnt;
    __syncthreads();
    for (int off = 1; off < 1024; off <<= 1) {
        const unsigned int v = sc[t];
        const unsigned int add = (t >= off) ? sc[t - off] : 0u;
        __syncthreads();
        sc[t] = v + add;
        __syncthreads();
    }
    unsigned int base = sc[t] - mycnt;   // exclusive prefix, ascending n
    unsigned short* lc = lists + (size_t)c * Nn;
    unsigned int wrd = word;
    while (wrd) {
        const int j = __ffs(wrd) - 1;
        lc[base++] = (unsigned short)(r0 + j);
        wrd &= wrd - 1;
    }
    if (t == 1023) cnt[c] = sc[1023];
}

// ---- refine v3 (round-6 proven, unchanged) ----
#define NGB 8
__global__ void __launch_bounds__(256, 1)
k_refine(const float* __restrict__ xT, const float* __restrict__ w,
         const float* __restrict__ sw2, const float* __restrict__ cn,
         const unsigned int* __restrict__ cnt, const unsigned short* __restrict__ lists,
         unsigned long long* __restrict__ keys) {
    __shared__ __align__(16) float xs[64 * 260];   // 66.5 KB
    __shared__ __align__(16) float ws[128 * 68];   // 34.8 KB
    __shared__ float cns[64];
    __shared__ unsigned short rid_s[64];
    const int c = blockIdx.x, gb = blockIdx.y;
    const int tid = threadIdx.x;
    const int cntc = (int)cnt[c];
    const int kl = tid & 31, rg = tid >> 5;   // rg 0..7
    float swk[4];
#pragma unroll
    for (int cc = 0; cc < 4; ++cc) swk[cc] = sw2[128 * c + kl + 32 * cc];

    for (int start = gb * 64; start < cntc; start += NGB * 64) {
#pragma unroll
        for (int m = 0; m < 16; ++m) {
            const int e = tid + 256 * m;      // 0..4095
            const int j = e >> 6, d4 = e & 63;
            const int li = min(start + j, cntc - 1);
            const int row = lists[(size_t)c * Nn + li];
            *reinterpret_cast<float4*>(&xs[j * 260 + 4 * d4]) =
                *reinterpret_cast<const float4*>(&xT[(size_t)row * Dd + 4 * d4]);
        }
        if (tid < 64) {
            const int li = min(start + tid, cntc - 1);
            const unsigned short row = lists[(size_t)c * Nn + li];
            rid_s[tid] = row;
            cns[tid] = cn[row];
        }
        __syncthreads();

        float acc[8][4];
#pragma unroll
        for (int rr = 0; rr < 8; ++rr)
#pragma unroll
            for (int cc = 0; cc < 4; ++cc) acc[rr][cc] = 0.0f;

        for (int step = 0; step < 4; ++step) {
#pragma unroll
            for (int m = 0; m < 8; ++m) {
                const int e = tid + 256 * m;  // 0..2047
                const int code = e >> 4, dseg = e & 15;
                *reinterpret_cast<float4*>(&ws[code * 68 + 4 * dseg]) =
                    *reinterpret_cast<const float4*>(
                        &w[(size_t)(128 * c + code) * Dd + step * 64 + 4 * dseg]);
            }
            __syncthreads();
#pragma unroll
            for (int dl = 0; dl < 16; ++dl) {
                float4 wv[4];
#pragma unroll
                for (int cc = 0; cc < 4; ++cc)
                    wv[cc] = *reinterpret_cast<const float4*>(
                        &ws[(kl + 32 * cc) * 68 + 4 * dl]);
#pragma unroll
                for (int rr = 0; rr < 8; ++rr) {
                    const float4 xv = *reinterpret_cast<const float4*>(
                        &xs[(8 * rg + rr) * 260 + step * 64 + 4 * dl]);
#pragma unroll
                    for (int cc = 0; cc < 4; ++cc) {
                        acc[rr][cc] = fmaf(xv.x, wv[cc].x, acc[rr][cc]);
                        acc[rr][cc] = fmaf(xv.y, wv[cc].y, acc[rr][cc]);
                        acc[rr][cc] = fmaf(xv.z, wv[cc].z, acc[rr][cc]);
                        acc[rr][cc] = fmaf(xv.w, wv[cc].w, acc[rr][cc]);
                    }
                }
            }
            __syncthreads();
        }

#pragma unroll
        for (int rr = 0; rr < 8; ++rr) {
            const int rl = 8 * rg + rr;
            const float cr = cns[rl];
            float bv = 3.402823466e+38f;
            int bk = 0x7FFFFFFF;
#pragma unroll
            for (int cc = 0; cc < 4; ++cc) {
                const float t1 = cr + swk[cc];                // fl32(cn + sw)
                const float s = fmaf(-2.0f, acc[rr][cc], t1); // fl32(t1 - 2*dot)
                const int k = 128 * c + kl + 32 * cc;
                if (s < bv || (s == bv && k < bk)) { bv = s; bk = k; }
            }
#pragma unroll
            for (int d = 1; d < 32; d <<= 1) {
                const float ov = __shfl_xor(bv, d);
                const int ok = __shfl_xor(bk, d);
                if (ov < bv || (ov == bv && ok < bk)) { bv = ov; bk = ok; }
            }
            if (kl == 0) {
                const unsigned long long key =
                    ((unsigned long long)__float_as_uint(bv) << 32) |
                    (unsigned long long)(unsigned int)bk;
                atomicMin(&keys[rid_s[rl]], key);
            }
        }
        __syncthreads();
    }
}

// ---- gather + STE + partial loss (proven, key-indexed) ----
__global__ void k_quant2(const float* __restrict__ x, const float* __restrict__ w,
                         const unsigned long long* __restrict__ keys,
                         float* __restrict__ outq, float* __restrict__ idxf,
                         double* __restrict__ part) {
#pragma clang fp contract(off)
    __shared__ double red[256];
    const int tid = threadIdx.x;
    const int n0 = blockIdx.x * 64;
    const int b = n0 >> 10, t0 = n0 & 1023;
    const int tl = tid & 63;
    const int d0 = tid >> 6;
    const int n = n0 + tl;
    const int code = (int)(unsigned int)(keys[n] & 0xFFFFFFFFULL);
    if (tid < 64) idxf[n0 + tid] = (float)(int)(unsigned int)(keys[n0 + tid] & 0xFFFFFFFFULL);
    const float* wr = w + (size_t)code * Dd;
    const size_t base = (size_t)b * (Dd * Tt) + t0 + tl;
    double s = 0.0;
    for (int d = d0; d < Dd; d += 4) {
        const float xv = x[base + (size_t)d * Tt];
        const float qv = wr[d];
        const float d1 = qv - xv;
        const float qs = xv + d1;
        const float d2 = qs - xv;
        s += (double)d2 * (double)d2;
        outq[base + (size_t)d * Tt] = qs;
    }
    red[tid] = s;
    __syncthreads();
    for (int st = 128; st > 0; st >>= 1) {
        if (tid < st) red[tid] += red[tid + st];
        __syncthreads();
    }
    if (tid == 0) part[blockIdx.x] = red[0];
}

__global__ void k_loss(const double* __restrict__ part, float* __restrict__ loss) {
    __shared__ double red[512];
    const int tid = threadIdx.x;
    red[tid] = part[tid];
    __syncthreads();
    for (int st = 256; st > 0; st >>= 1) {
        if (tid < st) red[tid] += red[tid + st];
        __syncthreads();
    }
    if (tid == 0)
        loss[0] = (float)(1.25 * red[0] / (double)((size_t)Bn * Dd * Tt));
}

// ===================== LEGACY (round-2 proven) FALLBACK =====================
__global__ void k_transpose(const float* __restrict__ w, float* __restrict__ wtg) {
    __shared__ float tile[32][33];
    const int k0 = blockIdx.x * 32;
    const int d0 = blockIdx.y * 32;
    const int tx = threadIdx.x, ty = threadIdx.y;
#pragma unroll
    for (int r = 0; r < 32; r += 8)
        tile[r + ty][tx] = w[(size_t)(k0 + r + ty) * Dd + d0 + tx];
    __syncthreads();
#pragma unroll
    for (int r = 0; r < 32; r += 8)
        wtg[(size_t)(d0 + r + ty) * Kk + k0 + tx] = tile[tx][r + ty];
}

__global__ void k_sumx2_np_legacy(const float* __restrict__ x, float* __restrict__ c) {
#pragma clang fp contract(off)
    const int n = blockIdx.x * 256 + threadIdx.x;
    const int b = n >> 10, t = n & 1023;
    const float* p = x + (size_t)b * (Dd * Tt) + t;
    float h[2];
#pragma unroll
    for (int half = 0; half < 2; ++half) {
        float r[8];
#pragma unroll
        for (int j = 0; j < 8; ++j) {
            const float v = p[(size_t)(half * 128 + j) * Tt];
            r[j] = v * v;
        }
        for (int i = 8; i < 128; i += 8) {
#pragma unroll
            for (int j = 0; j < 8; ++j) {
                const float v = p[(size_t)(half * 128 + i + j) * Tt];
                const float sq = v * v;
                r[j] = r[j] + sq;
            }
        }
        h[half] = ((r[0] + r[1]) + (r[2] + r[3])) + ((r[4] + r[5]) + (r[6] + r[7]));
    }
    c[n] = h[0] + h[1];
}

template <bool WTG>
__global__ void __launch_bounds__(512, 2)
k_argmin(const float* __restrict__ x, const float* __restrict__ w,
         const float* __restrict__ wtg, const float* __restrict__ sw2,
         const float* __restrict__ cn,
         int* __restrict__ idx_out, float* __restrict__ idx_f) {
    __shared__ __align__(16) float At[32][132];
    __shared__ __align__(16) float Wt[32][268];
    const int tid = threadIdx.x;
    const int n0 = blockIdx.x * 128;
    const int b = n0 >> 10;
    const int t0 = n0 & 1023;
    const int ty = tid >> 5;
    const int tx = tid & 31;
    const int r0 = ty * 4;
    const int c0 = tx * 4;
    const float* xb = x + (size_t)b * (Dd * Tt) + t0;

    float c8[8];
#pragma unroll
    for (int i = 0; i < 8; ++i) {
        const int row = (i < 4) ? (r0 + i) : (64 + r0 + (i - 4));
        c8[i] = cn[n0 + row];
    }
    float best[8];
    int bidx[8];
#pragma unroll
    for (int i = 0; i < 8; ++i) { best[i] = 3.402823466e+38f; bidx[i] = 0; }

    for (int kc = 0; kc < Kk; kc += 256) {
        float acc[8][8];
#pragma unroll
        for (int i = 0; i < 8; ++i)
#pragma unroll
            for (int j = 0; j < 8; ++j) acc[i][j] = 0.0f;
        for (int ds = 0; ds < Dd; ds += 32) {
#pragma unroll
            for (int u = 0; u < 2; ++u) {
                int cc = tid + 512 * u;
                int dd = cc >> 5, i4 = cc & 31;
                float4 v = *reinterpret_cast<const float4*>(
                    &xb[(size_t)(ds + dd) * Tt + i4 * 4]);
                *reinterpret_cast<float4*>(&At[dd][i4 * 4]) = v;
            }
            if (WTG) {
#pragma unroll
                for (int u = 0; u < 4; ++u) {
                    int cc = tid + 512 * u;
                    int dd = cc >> 6, j4 = cc & 63;
                    float4 v = *reinterpret_cast<const float4*>(
                        &wtg[(size_t)(ds + dd) * Kk + kc + j4 * 4]);
                    *reinterpret_cast<float4*>(&Wt[dd][j4 * 4]) = v;
                }
            } else {
#pragma unroll
                for (int u = 0; u < 4; ++u) {
                    int cc = tid + 512 * u;
                    int j = cc >> 3, m = cc & 7;
                    float4 v = *reinterpret_cast<const float4*>(
                        &w[(size_t)(kc + j) * Dd + ds + m * 4]);
                    Wt[m * 4 + 0][j] = v.x;
                    Wt[m * 4 + 1][j] = v.y;
                    Wt[m * 4 + 2][j] = v.z;
                    Wt[m * 4 + 3][j] = v.w;
                }
            }
            __syncthreads();
#pragma unroll 8
            for (int dd = 0; dd < 32; ++dd) {
                float4 a0 = *reinterpret_cast<const float4*>(&At[dd][r0]);
                float4 a1 = *reinterpret_cast<const float4*>(&At[dd][64 + r0]);
                float4 b0 = *reinterpret_cast<const float4*>(&Wt[dd][c0]);
                float4 b1 = *reinterpret_cast<const float4*>(&Wt[dd][128 + c0]);
                float av[8] = {a0.x, a0.y, a0.z, a0.w, a1.x, a1.y, a1.z, a1.w};
                float bv[8] = {b0.x, b0.y, b0.z, b0.w, b1.x, b1.y, b1.z, b1.w};
#pragma unroll
                for (int i = 0; i < 8; ++i)
#pragma unroll
                    for (int j = 0; j < 8; ++j)
                        acc[i][j] = fmaf(av[i], bv[j], acc[i][j]);
            }
            __syncthreads();
        }
#pragma unroll
        for (int j = 0; j < 8; ++j) {
            const int col = (j < 4) ? (c0 + j) : (128 + c0 + (j - 4));
            const int k = kc + col;
            const float sw = sw2[k];
#pragma unroll
            for (int i = 0; i < 8; ++i) {
                const float t1 = c8[i] + sw;
                const float s = fmaf(-2.0f, acc[i][j], t1);
                if (s < best[i] || (s == best[i] && k < bidx[i])) {
                    best[i] = s; bidx[i] = k;
                }
            }
        }
    }
#pragma unroll
    for (int i = 0; i < 8; ++i) {
        float v = best[i];
        int id = bidx[i];
#pragma unroll
        for (int m = 1; m < 32; m <<= 1) {
            const float ov = __shfl_xor(v, m);
            const int oi = __shfl_xor(id, m);
            if (ov < v || (ov == v && oi < id)) { v = ov; id = oi; }
        }
        if (tx == 0) {
            const int row = (i < 4) ? (r0 + i) : (64 + r0 + (i - 4));
            const int n = n0 + row;
            idx_out[n] = id;
            idx_f[n] = (float)id;
        }
    }
}

__global__ void k_quant(const float* __restrict__ x, const float* __restrict__ w,
                        const int* __restrict__ idx, float* __restrict__ outq,
                        double* __restrict__ part) {
#pragma clang fp contract(off)
    __shared__ double red[256];
    const int tid = threadIdx.x;
    const int n0 = blockIdx.x * 64;
    const int b = n0 >> 10, t0 = n0 & 1023;
    const int tl = tid & 63;
    const int d0 = tid >> 6;
    const int n = n0 + tl;
    const int code = idx[n];
    const float* wr = w + (size_t)code * Dd;
    const size_t base = (size_t)b * (Dd * Tt) + t0 + tl;
    double s = 0.0;
    for (int d = d0; d < Dd; d += 4) {
        const float xv = x[base + (size_t)d * Tt];
        const float qv = wr[d];
        const float d1 = qv - xv;
        const float qs = xv + d1;
        const float d2 = qs - xv;
        s += (double)d2 * (double)d2;
        outq[base + (size_t)d * Tt] = qs;
    }
    red[tid] = s;
    __syncthreads();
    for (int st = 128; st > 0; st >>= 1) {
        if (tid < st) red[tid] += red[tid + st];
        __syncthreads();
    }
    if (tid == 0) part[blockIdx.x] = red[0];
}

// ===================== host =====================
extern "C" void kernel_launch(void* const* d_in, const int* in_sizes, int n_in,
                              void* d_out, int out_size, void* d_ws, size_t ws_size,
                              hipStream_t stream) {
    const float* x = (const float*)d_in[0];
    const float* w = (const float*)d_in[1];
    float* out = (float*)d_out;
    float* loss = out;
    float* outq = out + 1;
    float* idxf = out + 1 + (size_t)Bn * Dd * Tt;
    char* ws = (char*)d_ws;

    if (ws_size >= WS_NEED) {
        float* xT = (float*)(ws + OFF_XT);
        short* xbt = (short*)(ws + OFF_XBT);
        short* wbt = (short*)(ws + OFF_WBT);
        float* cm = (float*)(ws + OFF_CM);
        unsigned long long* mask = (unsigned long long*)(ws + OFF_MASK); // aliases dead xbt
        unsigned short* lists = (unsigned short*)(ws + OFF_LIST);
        unsigned long long* keys = (unsigned long long*)(ws + OFF_KEYS);
        float* sw2 = (float*)(ws + OFF_SW2);
        float* cn = (float*)(ws + OFF_CN);
        unsigned int* cnt = (unsigned int*)(ws + OFF_CNT);
        double* part = (double*)(ws + OFF_PART);

        k_xprep<<<dim3(32, 8, 32), dim3(32, 8), 0, stream>>>(x, xT, xbt);
        k_wbf<<<(Kk * Dd) / 1024, 256, 0, stream>>>(w, wbt);
        k_sumx2_np<<<Nn / 128, 128, 0, stream>>>(x, cn);
        k_sumw2_np<<<Kk / 256, 256, 0, stream>>>(w, sw2);
        k_mfma_filter<<<dim3(Nn / 128, 2), 512, 0, stream>>>(xbt, wbt, sw2, cm);
        k_mask<<<Nn / 256, 256, 0, stream>>>(cm, cn, mask, keys);
        k_compact<<<64, 1024, 0, stream>>>(mask, cnt, lists);
        k_refine<<<dim3(64, NGB), 256, 0, stream>>>(xT, w, sw2, cn, cnt, lists, keys);
        k_quant2<<<Nn / 64, 256, 0, stream>>>(x, w, keys, outq, idxf, part);
        k_loss<<<1, 512, 0, stream>>>(part, loss);
    } else {
        // legacy round-2 path
        float* sw2 = (float*)(ws);
        int* idx = (int*)(ws + 32768);
        double* part = (double*)(ws + 163840);
        float* cn = (float*)(ws + 172032);
        float* wtg = (float*)(ws + 524288);
        const bool use_wtg = ws_size >= (size_t)524288 + (size_t)Kk * Dd * 4;
        if (use_wtg)
            k_transpose<<<dim3(Kk / 32, Dd / 32), dim3(32, 8), 0, stream>>>(w, wtg);
        k_sumx2_np_legacy<<<Nn / 256, 256, 0, stream>>>(x, cn);
        k_sumw2_np<<<Kk / 256, 256, 0, stream>>>(w, sw2);
        if (use_wtg)
            k_argmin<true><<<Nn / 128, 512, 0, stream>>>(x, w, wtg, sw2, cn, idx, idxf);
        else
            k_argmin<false><<<Nn / 128, 512, 0, stream>>>(x, w, wtg, sw2, cn, idx, idxf);
        k_quant<<<Nn / 64, 256, 0, stream>>>(x, w, idx, outq, part);
        k_loss<<<1, 512, 0, stream>>>(part, loss);
    }
}

// Round 16
// 426.468 us; speedup vs baseline: 1.1237x; 1.1237x over previous
//
#include <hip/hip_runtime.h>
#include <hip/hip_bf16.h>

#define Bn 32
#define Dd 256
#define Tt 1024
#define Nn (Bn * Tt)   // 32768
#define Kk 8192

typedef __attribute__((ext_vector_type(8))) short bf16x8;
typedef __attribute__((ext_vector_type(4))) float f32x4;

static __device__ __forceinline__ short f2bf(float v) {
    __hip_bfloat16 h = __float2bfloat16(v);
    return *reinterpret_cast<short*>(&h);
}

// ===================== ws layout (total == proven 75927808) ====================
#define OFF_XT    0ULL            // f32 [32768][256]  32 MB
#define OFF_XBT   33554432ULL     // bf16 [32768][256] 16 MB (dead after filter -> mask reuses)
#define OFF_WBT   50331648ULL     // bf16 fragment-ordered [64 chunks][4096 units][8]  4 MB
#define OFF_CM    54525952ULL     // f32 [32768][128]  16 MB  (chunk-min, col=2c+cp)
#define OFF_LIST  71303168ULL     // u16 [64][32768]    4 MB
#define OFF_KEYS  75497472ULL     // u64 [32768]      256 KB
#define OFF_SW2   75759616ULL     // f32 [8192]
#define OFF_CN    75792384ULL     // f32 [32768]
#define OFF_CNT   75923456ULL     // u32 [64]
#define OFF_PART  75923712ULL     // f64 [512]
#define WS_NEED   75927808ULL
#define OFF_MASK  OFF_XBT         // u64 [32768] 256 KB, aliases dead xbt

// ---- prep: x [b][d][t] -> xT f32 [n][d], xbt bf16 [n][d] ----
__global__ void k_xprep(const float* __restrict__ x, float* __restrict__ xT,
                        short* __restrict__ xbt) {
    __shared__ float tile[32][33];
    const int b = blockIdx.z, d0 = blockIdx.y * 32, t0 = blockIdx.x * 32;
    const int tx = threadIdx.x, ty = threadIdx.y;
#pragma unroll
    for (int r = 0; r < 32; r += 8)
        tile[ty + r][tx] = x[((size_t)(b * Dd + d0 + ty + r)) * Tt + t0 + tx];
    __syncthreads();
#pragma unroll
    for (int r = 0; r < 32; r += 8) {
        const size_t o = (size_t)(b * Tt + t0 + ty + r) * Dd + d0 + tx;
        const float v = tile[tx][ty + r];
        xT[o] = v;
        xbt[o] = f2bf(v);
    }
}

// ---- prep: w -> bf16 in FRAGMENT ORDER (v6's verified inverse map) ----
// unit e of chunk c holds w[(128c+16g+fl15)*256 + 32ks + 8*fl4 .. +8) where
// g=e>>9, ks=(e>>6)&7, fl4=(e>>4)&3, fl15=e&15. Writes coalesced; reads are
// 32B granules from L2-resident w.
__global__ void k_wbf_frag(const float* __restrict__ w, short* __restrict__ wf) {
    const int u = blockIdx.x * 256 + threadIdx.x;   // 0..262143
    const int c = u >> 12, e = u & 4095;
    const int g = e >> 9, ks = (e >> 6) & 7, fl4 = (e >> 4) & 3, fl15 = e & 15;
    const float* src = &w[(size_t)(128 * c + 16 * g + fl15) * Dd + ks * 32 + fl4 * 8];
    const float4 v0 = *reinterpret_cast<const float4*>(src);
    const float4 v1 = *reinterpret_cast<const float4*>(src + 4);
    short o[8];
    o[0] = f2bf(v0.x); o[1] = f2bf(v0.y); o[2] = f2bf(v0.z); o[3] = f2bf(v0.w);
    o[4] = f2bf(v1.x); o[5] = f2bf(v1.y); o[6] = f2bf(v1.z); o[7] = f2bf(v1.w);
    *reinterpret_cast<bf16x8*>(&wf[(size_t)u * 8]) = *reinterpret_cast<const bf16x8*>(o);
}

// ---- numpy-pairwise-exact sum of squares (proven round 2; round-9 grid) ----
__global__ void k_sumx2_np(const float* __restrict__ x, float* __restrict__ c) {
#pragma clang fp contract(off)
    const int n = blockIdx.x * 128 + threadIdx.x;
    const int b = n >> 10, t = n & 1023;
    const float* p = x + (size_t)b * (Dd * Tt) + t;
    float h[2];
#pragma unroll
    for (int half = 0; half < 2; ++half) {
        float r[8];
#pragma unroll
        for (int j = 0; j < 8; ++j) {
            const float v = p[(size_t)(half * 128 + j) * Tt];
            r[j] = v * v;
        }
        for (int i = 8; i < 128; i += 8) {
#pragma unroll
            for (int j = 0; j < 8; ++j) {
                const float v = p[(size_t)(half * 128 + i + j) * Tt];
                const float sq = v * v;
                r[j] = r[j] + sq;
            }
        }
        h[half] = ((r[0] + r[1]) + (r[2] + r[3])) + ((r[4] + r[5]) + (r[6] + r[7]));
    }
    c[n] = h[0] + h[1];
}

__global__ void k_sumw2_np(const float* __restrict__ w, float* __restrict__ sw) {
#pragma clang fp contract(off)
    const int k = blockIdx.x * 256 + threadIdx.x;
    const float* p = w + (size_t)k * Dd;
    float h[2];
#pragma unroll
    for (int half = 0; half < 2; ++half) {
        float r[8];
#pragma unroll
        for (int j = 0; j < 8; ++j) {
            const float v = p[half * 128 + j];
            r[j] = v * v;
        }
        for (int i = 8; i < 128; i += 8) {
#pragma unroll
            for (int j = 0; j < 8; ++j) {
                const float v = p[half * 128 + i + j];
                const float sq = v * v;
                r[j] = r[j] + sq;
            }
        }
        h[half] = ((r[0] + r[1]) + (r[2] + r[3])) + ((r[4] + r[5]) + (r[6] + r[7]));
    }
    sw[k] = h[0] + h[1];
}

// ---- stage 1: bf16 MFMA filter v7 — coalesced linear staging (round-8's
// measured-fast global pattern) + fragment-ordered LDS (v6's measured-0-conflict
// layout on BOTH sides). wbt is pre-permuted by k_wbf_frag.
__global__ void __launch_bounds__(512, 4)
k_mfma_filter(const short* __restrict__ xbt, const short* __restrict__ wbt,
              const float* __restrict__ sw2, float* __restrict__ cm) {
    __shared__ __align__(16) short Wf[32768];   // 64 KB, fragment-ordered
    const int tid = threadIdx.x;
    const int n0 = blockIdx.x * 128;
    const int cbase = blockIdx.y * 32;
    const int wid = tid >> 6, lane = tid & 63;
    const int rp = wid >> 1, cp = wid & 1;
    const int l15 = lane & 15, l4 = lane >> 4;

    bf16x8 a[2][8];
#pragma unroll
    for (int rt = 0; rt < 2; ++rt)
#pragma unroll
        for (int ks = 0; ks < 8; ++ks)
            a[rt][ks] = *reinterpret_cast<const bf16x8*>(
                &xbt[(size_t)(n0 + 32 * rp + 16 * rt + l15) * Dd + 32 * ks + 8 * l4]);

    for (int cc = 0; cc < 32; ++cc) {
        const int c = cbase + cc;
        const short* wc = wbt + (size_t)c * 32768;   // chunk base (4096 units)
#pragma unroll
        for (int m = 0; m < 8; ++m) {
            const int e = tid + 512 * m;             // linear: global AND LDS
            *reinterpret_cast<bf16x8*>(&Wf[e * 8]) =
                *reinterpret_cast<const bf16x8*>(&wc[(size_t)e * 8]);
        }
        __syncthreads();

        f32x4 acc[2][4];
#pragma unroll
        for (int rt = 0; rt < 2; ++rt)
#pragma unroll
            for (int ct = 0; ct < 4; ++ct) acc[rt][ct] = (f32x4)0.0f;

#pragma unroll
        for (int ks = 0; ks < 8; ++ks) {
            bf16x8 b[4];
#pragma unroll
            for (int ct = 0; ct < 4; ++ct)
                b[ct] = *reinterpret_cast<const bf16x8*>(
                    &Wf[(((4 * cp + ct) * 8 + ks) * 64 + lane) * 8]);
#pragma unroll
            for (int rt = 0; rt < 2; ++rt)
#pragma unroll
                for (int ct = 0; ct < 4; ++ct)
                    acc[rt][ct] = __builtin_amdgcn_mfma_f32_16x16x32_bf16(
                        a[rt][ks], b[ct], acc[rt][ct], 0, 0, 0);
        }
        __syncthreads();   // Wf reads done; next iteration may restage

        float swc[4];
#pragma unroll
        for (int ct = 0; ct < 4; ++ct)
            swc[ct] = sw2[128 * c + 64 * cp + 16 * ct + l15];
#pragma unroll
        for (int rt = 0; rt < 2; ++rt) {
#pragma unroll
            for (int r = 0; r < 4; ++r) {
                float mm = fmaf(-2.0f, acc[rt][0][r], swc[0]);
#pragma unroll
                for (int ct = 1; ct < 4; ++ct)
                    mm = fminf(mm, fmaf(-2.0f, acc[rt][ct][r], swc[ct]));
#pragma unroll
                for (int d = 1; d < 16; d <<= 1)
                    mm = fminf(mm, __shfl_xor(mm, d));
                if (l15 == 0) {
                    const int row = n0 + 32 * rp + 16 * rt + 4 * l4 + r;
                    cm[(size_t)row * 128 + 2 * c + cp] = mm;   // [n][128], race-free
                }
            }
        }
    }
}

// ---- mask: per-row chunk mask over 128 cm columns (round-8 proven) ----
__global__ void __launch_bounds__(256)
k_mask(const float* __restrict__ cm, const float* __restrict__ cn,
       unsigned long long* __restrict__ mask, unsigned long long* __restrict__ keys) {
    const int tid = threadIdx.x;
    const int lane = tid & 63, w = tid >> 6;
    const int grp = lane >> 4, sub = lane & 15;
    const int n0 = blockIdx.x * 256;
    for (int pass = 0; pass < 16; ++pass) {
        const int row = n0 + pass * 16 + 4 * w + grp;
        const float4 v0 = *reinterpret_cast<const float4*>(&cm[(size_t)row * 128 + 8 * sub]);
        const float4 v1 = *reinterpret_cast<const float4*>(&cm[(size_t)row * 128 + 8 * sub + 4]);
        float gmin = fminf(fminf(fminf(v0.x, v0.y), fminf(v0.z, v0.w)),
                           fminf(fminf(v1.x, v1.y), fminf(v1.z, v1.w)));
#pragma unroll
        for (int m = 1; m < 16; m <<= 1) gmin = fminf(gmin, __shfl_xor(gmin, m));
        const float margin = 7.1e-5f + 2.6e-5f * sqrtf(cn[row]);
        const float thr = gmin + margin;
        unsigned int nib = 0;
        if (fminf(v0.x, v0.y) <= thr) nib |= 1u;
        if (fminf(v0.z, v0.w) <= thr) nib |= 2u;
        if (fminf(v1.x, v1.y) <= thr) nib |= 4u;
        if (fminf(v1.z, v1.w) <= thr) nib |= 8u;
        unsigned long long mk = (unsigned long long)nib << (4 * sub);
#pragma unroll
        for (int m = 1; m < 16; m <<= 1) mk |= __shfl_xor(mk, m);
        if (sub == 0) {
            mask[row] = mk;
            keys[row] = 0xFFFFFFFFFFFFFFFFULL;
        }
    }
}

// ---- compact: per-chunk candidate list via block prefix sum (proven round 7) ----
__global__ void __launch_bounds__(1024)
k_compact(const unsigned long long* __restrict__ mask,
          unsigned int* __restrict__ cnt, unsigned short* __restrict__ lists) {
    __shared__ unsigned int sc[1024];
    const int c = blockIdx.x;
    const int t = threadIdx.x;
    const int r0 = t * 32;
    unsigned int word = 0;
#pragma unroll
    for (int j = 0; j < 32; ++j)
        word |= (unsigned int)((mask[r0 + j] >> c) & 1ULL) << j;
    const unsigned int mycnt = __popc(word);
    sc[t] = mycnt;
    __syncthreads();
    for (int off = 1; off < 1024; off <<= 1) {
        const unsigned int v = sc[t];
        const unsigned int add = (t >= off) ? sc[t - off] : 0u;
        __syncthreads();
        sc[t] = v + add;
        __syncthreads();
    }
    unsigned int base = sc[t] - mycnt;   // exclusive prefix, ascending n
    unsigned short* lc = lists + (size_t)c * Nn;
    unsigned int wrd = word;
    while (wrd) {
        const int j = __ffs(wrd) - 1;
        lc[base++] = (unsigned short)(r0 + j);
        wrd &= wrd - 1;
    }
    if (t == 1023) cnt[c] = sc[1023];
}

// ---- refine v3 (round-6 proven, unchanged) ----
#define NGB 8
__global__ void __launch_bounds__(256, 1)
k_refine(const float* __restrict__ xT, const float* __restrict__ w,
         const float* __restrict__ sw2, const float* __restrict__ cn,
         const unsigned int* __restrict__ cnt, const unsigned short* __restrict__ lists,
         unsigned long long* __restrict__ keys) {
    __shared__ __align__(16) float xs[64 * 260];   // 66.5 KB
    __shared__ __align__(16) float ws[128 * 68];   // 34.8 KB
    __shared__ float cns[64];
    __shared__ unsigned short rid_s[64];
    const int c = blockIdx.x, gb = blockIdx.y;
    const int tid = threadIdx.x;
    const int cntc = (int)cnt[c];
    const int kl = tid & 31, rg = tid >> 5;   // rg 0..7
    float swk[4];
#pragma unroll
    for (int cc = 0; cc < 4; ++cc) swk[cc] = sw2[128 * c + kl + 32 * cc];

    for (int start = gb * 64; start < cntc; start += NGB * 64) {
#pragma unroll
        for (int m = 0; m < 16; ++m) {
            const int e = tid + 256 * m;      // 0..4095
            const int j = e >> 6, d4 = e & 63;
            const int li = min(start + j, cntc - 1);
            const int row = lists[(size_t)c * Nn + li];
            *reinterpret_cast<float4*>(&xs[j * 260 + 4 * d4]) =
                *reinterpret_cast<const float4*>(&xT[(size_t)row * Dd + 4 * d4]);
        }
        if (tid < 64) {
            const int li = min(start + tid, cntc - 1);
            const unsigned short row = lists[(size_t)c * Nn + li];
            rid_s[tid] = row;
            cns[tid] = cn[row];
        }
        __syncthreads();

        float acc[8][4];
#pragma unroll
        for (int rr = 0; rr < 8; ++rr)
#pragma unroll
            for (int cc = 0; cc < 4; ++cc) acc[rr][cc] = 0.0f;

        for (int step = 0; step < 4; ++step) {
#pragma unroll
            for (int m = 0; m < 8; ++m) {
                const int e = tid + 256 * m;  // 0..2047
                const int code = e >> 4, dseg = e & 15;
                *reinterpret_cast<float4*>(&ws[code * 68 + 4 * dseg]) =
                    *reinterpret_cast<const float4*>(
                        &w[(size_t)(128 * c + code) * Dd + step * 64 + 4 * dseg]);
            }
            __syncthreads();
#pragma unroll
            for (int dl = 0; dl < 16; ++dl) {
                float4 wv[4];
#pragma unroll
                for (int cc = 0; cc < 4; ++cc)
                    wv[cc] = *reinterpret_cast<const float4*>(
                        &ws[(kl + 32 * cc) * 68 + 4 * dl]);
#pragma unroll
                for (int rr = 0; rr < 8; ++rr) {
                    const float4 xv = *reinterpret_cast<const float4*>(
                        &xs[(8 * rg + rr) * 260 + step * 64 + 4 * dl]);
#pragma unroll
                    for (int cc = 0; cc < 4; ++cc) {
                        acc[rr][cc] = fmaf(xv.x, wv[cc].x, acc[rr][cc]);
                        acc[rr][cc] = fmaf(xv.y, wv[cc].y, acc[rr][cc]);
                        acc[rr][cc] = fmaf(xv.z, wv[cc].z, acc[rr][cc]);
                        acc[rr][cc] = fmaf(xv.w, wv[cc].w, acc[rr][cc]);
                    }
                }
            }
            __syncthreads();
        }

#pragma unroll
        for (int rr = 0; rr < 8; ++rr) {
            const int rl = 8 * rg + rr;
            const float cr = cns[rl];
            float bv = 3.402823466e+38f;
            int bk = 0x7FFFFFFF;
#pragma unroll
            for (int cc = 0; cc < 4; ++cc) {
                const float t1 = cr + swk[cc];                // fl32(cn + sw)
                const float s = fmaf(-2.0f, acc[rr][cc], t1); // fl32(t1 - 2*dot)
                const int k = 128 * c + kl + 32 * cc;
                if (s < bv || (s == bv && k < bk)) { bv = s; bk = k; }
            }
#pragma unroll
            for (int d = 1; d < 32; d <<= 1) {
                const float ov = __shfl_xor(bv, d);
                const int ok = __shfl_xor(bk, d);
                if (ov < bv || (ov == bv && ok < bk)) { bv = ov; bk = ok; }
            }
            if (kl == 0) {
                const unsigned long long key =
                    ((unsigned long long)__float_as_uint(bv) << 32) |
                    (unsigned long long)(unsigned int)bk;
                atomicMin(&keys[rid_s[rl]], key);
            }
        }
        __syncthreads();
    }
}

// ---- gather + STE + partial loss (proven, key-indexed) ----
__global__ void k_quant2(const float* __restrict__ x, const float* __restrict__ w,
                         const unsigned long long* __restrict__ keys,
                         float* __restrict__ outq, float* __restrict__ idxf,
                         double* __restrict__ part) {
#pragma clang fp contract(off)
    __shared__ double red[256];
    const int tid = threadIdx.x;
    const int n0 = blockIdx.x * 64;
    const int b = n0 >> 10, t0 = n0 & 1023;
    const int tl = tid & 63;
    const int d0 = tid >> 6;
    const int n = n0 + tl;
    const int code = (int)(unsigned int)(keys[n] & 0xFFFFFFFFULL);
    if (tid < 64) idxf[n0 + tid] = (float)(int)(unsigned int)(keys[n0 + tid] & 0xFFFFFFFFULL);
    const float* wr = w + (size_t)code * Dd;
    const size_t base = (size_t)b * (Dd * Tt) + t0 + tl;
    double s = 0.0;
    for (int d = d0; d < Dd; d += 4) {
        const float xv = x[base + (size_t)d * Tt];
        const float qv = wr[d];
        const float d1 = qv - xv;
        const float qs = xv + d1;
        const float d2 = qs - xv;
        s += (double)d2 * (double)d2;
        outq[base + (size_t)d * Tt] = qs;
    }
    red[tid] = s;
    __syncthreads();
    for (int st = 128; st > 0; st >>= 1) {
        if (tid < st) red[tid] += red[tid + st];
        __syncthreads();
    }
    if (tid == 0) part[blockIdx.x] = red[0];
}

__global__ void k_loss(const double* __restrict__ part, float* __restrict__ loss) {
    __shared__ double red[512];
    const int tid = threadIdx.x;
    red[tid] = part[tid];
    __syncthreads();
    for (int st = 256; st > 0; st >>= 1) {
        if (tid < st) red[tid] += red[tid + st];
        __syncthreads();
    }
    if (tid == 0)
        loss[0] = (float)(1.25 * red[0] / (double)((size_t)Bn * Dd * Tt));
}

// ===================== LEGACY (round-2 proven) FALLBACK =====================
__global__ void k_transpose(const float* __restrict__ w, float* __restrict__ wtg) {
    __shared__ float tile[32][33];
    const int k0 = blockIdx.x * 32;
    const int d0 = blockIdx.y * 32;
    const int tx = threadIdx.x, ty = threadIdx.y;
#pragma unroll
    for (int r = 0; r < 32; r += 8)
        tile[r + ty][tx] = w[(size_t)(k0 + r + ty) * Dd + d0 + tx];
    __syncthreads();
#pragma unroll
    for (int r = 0; r < 32; r += 8)
        wtg[(size_t)(d0 + r + ty) * Kk + k0 + tx] = tile[tx][r + ty];
}

__global__ void k_sumx2_np_legacy(const float* __restrict__ x, float* __restrict__ c) {
#pragma clang fp contract(off)
    const int n = blockIdx.x * 256 + threadIdx.x;
    const int b = n >> 10, t = n & 1023;
    const float* p = x + (size_t)b * (Dd * Tt) + t;
    float h[2];
#pragma unroll
    for (int half = 0; half < 2; ++half) {
        float r[8];
#pragma unroll
        for (int j = 0; j < 8; ++j) {
            const float v = p[(size_t)(half * 128 + j) * Tt];
            r[j] = v * v;
        }
        for (int i = 8; i < 128; i += 8) {
#pragma unroll
            for (int j = 0; j < 8; ++j) {
                const float v = p[(size_t)(half * 128 + i + j) * Tt];
                const float sq = v * v;
                r[j] = r[j] + sq;
            }
        }
        h[half] = ((r[0] + r[1]) + (r[2] + r[3])) + ((r[4] + r[5]) + (r[6] + r[7]));
    }
    c[n] = h[0] + h[1];
}

template <bool WTG>
__global__ void __launch_bounds__(512, 2)
k_argmin(const float* __restrict__ x, const float* __restrict__ w,
         const float* __restrict__ wtg, const float* __restrict__ sw2,
         const float* __restrict__ cn,
         int* __restrict__ idx_out, float* __restrict__ idx_f) {
    __shared__ __align__(16) float At[32][132];
    __shared__ __align__(16) float Wt[32][268];
    const int tid = threadIdx.x;
    const int n0 = blockIdx.x * 128;
    const int b = n0 >> 10;
    const int t0 = n0 & 1023;
    const int ty = tid >> 5;
    const int tx = tid & 31;
    const int r0 = ty * 4;
    const int c0 = tx * 4;
    const float* xb = x + (size_t)b * (Dd * Tt) + t0;

    float c8[8];
#pragma unroll
    for (int i = 0; i < 8; ++i) {
        const int row = (i < 4) ? (r0 + i) : (64 + r0 + (i - 4));
        c8[i] = cn[n0 + row];
    }
    float best[8];
    int bidx[8];
#pragma unroll
    for (int i = 0; i < 8; ++i) { best[i] = 3.402823466e+38f; bidx[i] = 0; }

    for (int kc = 0; kc < Kk; kc += 256) {
        float acc[8][8];
#pragma unroll
        for (int i = 0; i < 8; ++i)
#pragma unroll
            for (int j = 0; j < 8; ++j) acc[i][j] = 0.0f;
        for (int ds = 0; ds < Dd; ds += 32) {
#pragma unroll
            for (int u = 0; u < 2; ++u) {
                int cc = tid + 512 * u;
                int dd = cc >> 5, i4 = cc & 31;
                float4 v = *reinterpret_cast<const float4*>(
                    &xb[(size_t)(ds + dd) * Tt + i4 * 4]);
                *reinterpret_cast<float4*>(&At[dd][i4 * 4]) = v;
            }
            if (WTG) {
#pragma unroll
                for (int u = 0; u < 4; ++u) {
                    int cc = tid + 512 * u;
                    int dd = cc >> 6, j4 = cc & 63;
                    float4 v = *reinterpret_cast<const float4*>(
                        &wtg[(size_t)(ds + dd) * Kk + kc + j4 * 4]);
                    *reinterpret_cast<float4*>(&Wt[dd][j4 * 4]) = v;
                }
            } else {
#pragma unroll
                for (int u = 0; u < 4; ++u) {
                    int cc = tid + 512 * u;
                    int j = cc >> 3, m = cc & 7;
                    float4 v = *reinterpret_cast<const float4*>(
                        &w[(size_t)(kc + j) * Dd + ds + m * 4]);
                    Wt[m * 4 + 0][j] = v.x;
                    Wt[m * 4 + 1][j] = v.y;
                    Wt[m * 4 + 2][j] = v.z;
                    Wt[m * 4 + 3][j] = v.w;
                }
            }
            __syncthreads();
#pragma unroll 8
            for (int dd = 0; dd < 32; ++dd) {
                float4 a0 = *reinterpret_cast<const float4*>(&At[dd][r0]);
                float4 a1 = *reinterpret_cast<const float4*>(&At[dd][64 + r0]);
                float4 b0 = *reinterpret_cast<const float4*>(&Wt[dd][c0]);
                float4 b1 = *reinterpret_cast<const float4*>(&Wt[dd][128 + c0]);
                float av[8] = {a0.x, a0.y, a0.z, a0.w, a1.x, a1.y, a1.z, a1.w};
                float bv[8] = {b0.x, b0.y, b0.z, b0.w, b1.x, b1.y, b1.z, b1.w};
#pragma unroll
                for (int i = 0; i < 8; ++i)
#pragma unroll
                    for (int j = 0; j < 8; ++j)
                        acc[i][j] = fmaf(av[i], bv[j], acc[i][j]);
            }
            __syncthreads();
        }
#pragma unroll
        for (int j = 0; j < 8; ++j) {
            const int col = (j < 4) ? (c0 + j) : (128 + c0 + (j - 4));
            const int k = kc + col;
            const float sw = sw2[k];
#pragma unroll
            for (int i = 0; i < 8; ++i) {
                const float t1 = c8[i] + sw;
                const float s = fmaf(-2.0f, acc[i][j], t1);
                if (s < best[i] || (s == best[i] && k < bidx[i])) {
                    best[i] = s; bidx[i] = k;
                }
            }
        }
    }
#pragma unroll
    for (int i = 0; i < 8; ++i) {
        float v = best[i];
        int id = bidx[i];
#pragma unroll
        for (int m = 1; m < 32; m <<= 1) {
            const float ov = __shfl_xor(v, m);
            const int oi = __shfl_xor(id, m);
            if (ov < v || (ov == v && oi < id)) { v = ov; id = oi; }
        }
        if (tx == 0) {
            const int row = (i < 4) ? (r0 + i) : (64 + r0 + (i - 4));
            const int n = n0 + row;
            idx_out[n] = id;
            idx_f[n] = (float)id;
        }
    }
}

__global__ void k_quant(const float* __restrict__ x, const float* __restrict__ w,
                        const int* __restrict__ idx, float* __restrict__ outq,
                        double* __restrict__ part) {
#pragma clang fp contract(off)
    __shared__ double red[256];
    const int tid = threadIdx.x;
    const int n0 = blockIdx.x * 64;
    const int b = n0 >> 10, t0 = n0 & 1023;
    const int tl = tid & 63;
    const int d0 = tid >> 6;
    const int n = n0 + tl;
    const int code = idx[n];
    const float* wr = w + (size_t)code * Dd;
    const size_t base = (size_t)b * (Dd * Tt) + t0 + tl;
    double s = 0.0;
    for (int d = d0; d < Dd; d += 4) {
        const float xv = x[base + (size_t)d * Tt];
        const float qv = wr[d];
        const float d1 = qv - xv;
        const float qs = xv + d1;
        const float d2 = qs - xv;
        s += (double)d2 * (double)d2;
        outq[base + (size_t)d * Tt] = qs;
    }
    red[tid] = s;
    __syncthreads();
    for (int st = 128; st > 0; st >>= 1) {
        if (tid < st) red[tid] += red[tid + st];
        __syncthreads();
    }
    if (tid == 0) part[blockIdx.x] = red[0];
}

// ===================== host =====================
extern "C" void kernel_launch(void* const* d_in, const int* in_sizes, int n_in,
                              void* d_out, int out_size, void* d_ws, size_t ws_size,
                              hipStream_t stream) {
    const float* x = (const float*)d_in[0];
    const float* w = (const float*)d_in[1];
    float* out = (float*)d_out;
    float* loss = out;
    float* outq = out + 1;
    float* idxf = out + 1 + (size_t)Bn * Dd * Tt;
    char* ws = (char*)d_ws;

    if (ws_size >= WS_NEED) {
        float* xT = (float*)(ws + OFF_XT);
        short* xbt = (short*)(ws + OFF_XBT);
        short* wbt = (short*)(ws + OFF_WBT);
        float* cm = (float*)(ws + OFF_CM);
        unsigned long long* mask = (unsigned long long*)(ws + OFF_MASK); // aliases dead xbt
        unsigned short* lists = (unsigned short*)(ws + OFF_LIST);
        unsigned long long* keys = (unsigned long long*)(ws + OFF_KEYS);
        float* sw2 = (float*)(ws + OFF_SW2);
        float* cn = (float*)(ws + OFF_CN);
        unsigned int* cnt = (unsigned int*)(ws + OFF_CNT);
        double* part = (double*)(ws + OFF_PART);

        k_xprep<<<dim3(32, 8, 32), dim3(32, 8), 0, stream>>>(x, xT, xbt);
        k_wbf_frag<<<(Kk * Dd / 8) / 256, 256, 0, stream>>>(w, wbt);
        k_sumx2_np<<<Nn / 128, 128, 0, stream>>>(x, cn);
        k_sumw2_np<<<Kk / 256, 256, 0, stream>>>(w, sw2);
        k_mfma_filter<<<dim3(Nn / 128, 2), 512, 0, stream>>>(xbt, wbt, sw2, cm);
        k_mask<<<Nn / 256, 256, 0, stream>>>(cm, cn, mask, keys);
        k_compact<<<64, 1024, 0, stream>>>(mask, cnt, lists);
        k_refine<<<dim3(64, NGB), 256, 0, stream>>>(xT, w, sw2, cn, cnt, lists, keys);
        k_quant2<<<Nn / 64, 256, 0, stream>>>(x, w, keys, outq, idxf, part);
        k_loss<<<1, 512, 0, stream>>>(part, loss);
    } else {
        // legacy round-2 path
        float* sw2 = (float*)(ws);
        int* idx = (int*)(ws + 32768);
        double* part = (double*)(ws + 163840);
        float* cn = (float*)(ws + 172032);
        float* wtg = (float*)(ws + 524288);
        const bool use_wtg = ws_size >= (size_t)524288 + (size_t)Kk * Dd * 4;
        if (use_wtg)
            k_transpose<<<dim3(Kk / 32, Dd / 32), dim3(32, 8), 0, stream>>>(w, wtg);
        k_sumx2_np_legacy<<<Nn / 256, 256, 0, stream>>>(x, cn);
        k_sumw2_np<<<Kk / 256, 256, 0, stream>>>(w, sw2);
        if (use_wtg)
            k_argmin<true><<<Nn / 128, 512, 0, stream>>>(x, w, wtg, sw2, cn, idx, idxf);
        else
            k_argmin<false><<<Nn / 128, 512, 0, stream>>>(x, w, wtg, sw2, cn, idx, idxf);
        k_quant<<<Nn / 64, 256, 0, stream>>>(x, w, idx, outq, part);
        k_loss<<<1, 512, 0, stream>>>(part, loss);
    }
}

// Round 17
// 408.392 us; speedup vs baseline: 1.1735x; 1.0443x over previous
//
#include <hip/hip_runtime.h>
#include <hip/hip_bf16.h>

#define Bn 32
#define Dd 256
#define Tt 1024
#define Nn (Bn * Tt)   // 32768
#define Kk 8192

typedef __attribute__((ext_vector_type(8))) short bf16x8;
typedef __attribute__((ext_vector_type(4))) float f32x4;

static __device__ __forceinline__ short f2bf(float v) {
    __hip_bfloat16 h = __float2bfloat16(v);
    return *reinterpret_cast<short*>(&h);
}

// ===================== ws layout (total == proven 75927808) ====================
#define OFF_XT    0ULL            // f32 [32768][256]  32 MB
#define OFF_XBT   33554432ULL     // bf16 [32768][256] 16 MB (dead after filter -> mask reuses)
#define OFF_WBT   50331648ULL     // bf16 fragment-ordered [64 chunks][4096 units][8]  4 MB
#define OFF_CM    54525952ULL     // f32 [32768][128]  16 MB  (chunk-min, col=2c+cp)
#define OFF_LIST  71303168ULL     // u16 [64][32768]    4 MB
#define OFF_KEYS  75497472ULL     // u64 [32768]      256 KB
#define OFF_SW2   75759616ULL     // f32 [8192]
#define OFF_CN    75792384ULL     // f32 [32768]
#define OFF_CNT   75923456ULL     // u32 [64]
#define OFF_PART  75923712ULL     // f64 [512]
#define WS_NEED   75927808ULL
#define OFF_MASK  OFF_XBT         // u64 [32768] 256 KB, aliases dead xbt

// ---- prep: x [b][d][t] -> xT f32 [n][d], xbt bf16 [n][d] ----
__global__ void k_xprep(const float* __restrict__ x, float* __restrict__ xT,
                        short* __restrict__ xbt) {
    __shared__ float tile[32][33];
    const int b = blockIdx.z, d0 = blockIdx.y * 32, t0 = blockIdx.x * 32;
    const int tx = threadIdx.x, ty = threadIdx.y;
#pragma unroll
    for (int r = 0; r < 32; r += 8)
        tile[ty + r][tx] = x[((size_t)(b * Dd + d0 + ty + r)) * Tt + t0 + tx];
    __syncthreads();
#pragma unroll
    for (int r = 0; r < 32; r += 8) {
        const size_t o = (size_t)(b * Tt + t0 + ty + r) * Dd + d0 + tx;
        const float v = tile[tx][ty + r];
        xT[o] = v;
        xbt[o] = f2bf(v);
    }
}

// ---- prep: w -> bf16 in FRAGMENT ORDER (round-16 proven) ----
__global__ void k_wbf_frag(const float* __restrict__ w, short* __restrict__ wf) {
    const int u = blockIdx.x * 256 + threadIdx.x;   // 0..262143
    const int c = u >> 12, e = u & 4095;
    const int g = e >> 9, ks = (e >> 6) & 7, fl4 = (e >> 4) & 3, fl15 = e & 15;
    const float* src = &w[(size_t)(128 * c + 16 * g + fl15) * Dd + ks * 32 + fl4 * 8];
    const float4 v0 = *reinterpret_cast<const float4*>(src);
    const float4 v1 = *reinterpret_cast<const float4*>(src + 4);
    short o[8];
    o[0] = f2bf(v0.x); o[1] = f2bf(v0.y); o[2] = f2bf(v0.z); o[3] = f2bf(v0.w);
    o[4] = f2bf(v1.x); o[5] = f2bf(v1.y); o[6] = f2bf(v1.z); o[7] = f2bf(v1.w);
    *reinterpret_cast<bf16x8*>(&wf[(size_t)u * 8]) = *reinterpret_cast<const bf16x8*>(o);
}

// ---- numpy-pairwise-exact sum of squares (proven round 2; round-9 grid) ----
__global__ void k_sumx2_np(const float* __restrict__ x, float* __restrict__ c) {
#pragma clang fp contract(off)
    const int n = blockIdx.x * 128 + threadIdx.x;
    const int b = n >> 10, t = n & 1023;
    const float* p = x + (size_t)b * (Dd * Tt) + t;
    float h[2];
#pragma unroll
    for (int half = 0; half < 2; ++half) {
        float r[8];
#pragma unroll
        for (int j = 0; j < 8; ++j) {
            const float v = p[(size_t)(half * 128 + j) * Tt];
            r[j] = v * v;
        }
        for (int i = 8; i < 128; i += 8) {
#pragma unroll
            for (int j = 0; j < 8; ++j) {
                const float v = p[(size_t)(half * 128 + i + j) * Tt];
                const float sq = v * v;
                r[j] = r[j] + sq;
            }
        }
        h[half] = ((r[0] + r[1]) + (r[2] + r[3])) + ((r[4] + r[5]) + (r[6] + r[7]));
    }
    c[n] = h[0] + h[1];
}

__global__ void k_sumw2_np(const float* __restrict__ w, float* __restrict__ sw) {
#pragma clang fp contract(off)
    const int k = blockIdx.x * 256 + threadIdx.x;
    const float* p = w + (size_t)k * Dd;
    float h[2];
#pragma unroll
    for (int half = 0; half < 2; ++half) {
        float r[8];
#pragma unroll
        for (int j = 0; j < 8; ++j) {
            const float v = p[half * 128 + j];
            r[j] = v * v;
        }
        for (int i = 8; i < 128; i += 8) {
#pragma unroll
            for (int j = 0; j < 8; ++j) {
                const float v = p[half * 128 + i + j];
                const float sq = v * v;
                r[j] = r[j] + sq;
            }
        }
        h[half] = ((r[0] + r[1]) + (r[2] + r[3])) + ((r[4] + r[5]) + (r[6] + r[7]));
    }
    sw[k] = h[0] + h[1];
}

// ---- stage 1: bf16 MFMA filter v7 (round-16 proven: 0 conflicts, coalesced) ----
__global__ void __launch_bounds__(512, 4)
k_mfma_filter(const short* __restrict__ xbt, const short* __restrict__ wbt,
              const float* __restrict__ sw2, float* __restrict__ cm) {
    __shared__ __align__(16) short Wf[32768];   // 64 KB, fragment-ordered
    const int tid = threadIdx.x;
    const int n0 = blockIdx.x * 128;
    const int cbase = blockIdx.y * 32;
    const int wid = tid >> 6, lane = tid & 63;
    const int rp = wid >> 1, cp = wid & 1;
    const int l15 = lane & 15, l4 = lane >> 4;

    bf16x8 a[2][8];
#pragma unroll
    for (int rt = 0; rt < 2; ++rt)
#pragma unroll
        for (int ks = 0; ks < 8; ++ks)
            a[rt][ks] = *reinterpret_cast<const bf16x8*>(
                &xbt[(size_t)(n0 + 32 * rp + 16 * rt + l15) * Dd + 32 * ks + 8 * l4]);

    for (int cc = 0; cc < 32; ++cc) {
        const int c = cbase + cc;
        const short* wc = wbt + (size_t)c * 32768;   // chunk base (4096 units)
#pragma unroll
        for (int m = 0; m < 8; ++m) {
            const int e = tid + 512 * m;             // linear: global AND LDS
            *reinterpret_cast<bf16x8*>(&Wf[e * 8]) =
                *reinterpret_cast<const bf16x8*>(&wc[(size_t)e * 8]);
        }
        __syncthreads();

        f32x4 acc[2][4];
#pragma unroll
        for (int rt = 0; rt < 2; ++rt)
#pragma unroll
            for (int ct = 0; ct < 4; ++ct) acc[rt][ct] = (f32x4)0.0f;

#pragma unroll
        for (int ks = 0; ks < 8; ++ks) {
            bf16x8 b[4];
#pragma unroll
            for (int ct = 0; ct < 4; ++ct)
                b[ct] = *reinterpret_cast<const bf16x8*>(
                    &Wf[(((4 * cp + ct) * 8 + ks) * 64 + lane) * 8]);
#pragma unroll
            for (int rt = 0; rt < 2; ++rt)
#pragma unroll
                for (int ct = 0; ct < 4; ++ct)
                    acc[rt][ct] = __builtin_amdgcn_mfma_f32_16x16x32_bf16(
                        a[rt][ks], b[ct], acc[rt][ct], 0, 0, 0);
        }
        __syncthreads();   // Wf reads done; next iteration may restage

        float swc[4];
#pragma unroll
        for (int ct = 0; ct < 4; ++ct)
            swc[ct] = sw2[128 * c + 64 * cp + 16 * ct + l15];
#pragma unroll
        for (int rt = 0; rt < 2; ++rt) {
#pragma unroll
            for (int r = 0; r < 4; ++r) {
                float mm = fmaf(-2.0f, acc[rt][0][r], swc[0]);
#pragma unroll
                for (int ct = 1; ct < 4; ++ct)
                    mm = fminf(mm, fmaf(-2.0f, acc[rt][ct][r], swc[ct]));
#pragma unroll
                for (int d = 1; d < 16; d <<= 1)
                    mm = fminf(mm, __shfl_xor(mm, d));
                if (l15 == 0) {
                    const int row = n0 + 32 * rp + 16 * rt + 4 * l4 + r;
                    cm[(size_t)row * 128 + 2 * c + cp] = mm;   // [n][128], race-free
                }
            }
        }
    }
}

// ---- mask: per-row chunk mask over 128 cm columns (round-8 proven) ----
__global__ void __launch_bounds__(256)
k_mask(const float* __restrict__ cm, const float* __restrict__ cn,
       unsigned long long* __restrict__ mask, unsigned long long* __restrict__ keys) {
    const int tid = threadIdx.x;
    const int lane = tid & 63, w = tid >> 6;
    const int grp = lane >> 4, sub = lane & 15;
    const int n0 = blockIdx.x * 256;
    for (int pass = 0; pass < 16; ++pass) {
        const int row = n0 + pass * 16 + 4 * w + grp;
        const float4 v0 = *reinterpret_cast<const float4*>(&cm[(size_t)row * 128 + 8 * sub]);
        const float4 v1 = *reinterpret_cast<const float4*>(&cm[(size_t)row * 128 + 8 * sub + 4]);
        float gmin = fminf(fminf(fminf(v0.x, v0.y), fminf(v0.z, v0.w)),
                           fminf(fminf(v1.x, v1.y), fminf(v1.z, v1.w)));
#pragma unroll
        for (int m = 1; m < 16; m <<= 1) gmin = fminf(gmin, __shfl_xor(gmin, m));
        const float margin = 7.1e-5f + 2.6e-5f * sqrtf(cn[row]);
        const float thr = gmin + margin;
        unsigned int nib = 0;
        if (fminf(v0.x, v0.y) <= thr) nib |= 1u;
        if (fminf(v0.z, v0.w) <= thr) nib |= 2u;
        if (fminf(v1.x, v1.y) <= thr) nib |= 4u;
        if (fminf(v1.z, v1.w) <= thr) nib |= 8u;
        unsigned long long mk = (unsigned long long)nib << (4 * sub);
#pragma unroll
        for (int m = 1; m < 16; m <<= 1) mk |= __shfl_xor(mk, m);
        if (sub == 0) {
            mask[row] = mk;
            keys[row] = 0xFFFFFFFFFFFFFFFFULL;
        }
    }
}

// ---- compact: per-chunk candidate list via block prefix sum (proven round 7) ----
__global__ void __launch_bounds__(1024)
k_compact(const unsigned long long* __restrict__ mask,
          unsigned int* __restrict__ cnt, unsigned short* __restrict__ lists) {
    __shared__ unsigned int sc[1024];
    const int c = blockIdx.x;
    const int t = threadIdx.x;
    const int r0 = t * 32;
    unsigned int word = 0;
#pragma unroll
    for (int j = 0; j < 32; ++j)
        word |= (unsigned int)((mask[r0 + j] >> c) & 1ULL) << j;
    const unsigned int mycnt = __popc(word);
    sc[t] = mycnt;
    __syncthreads();
    for (int off = 1; off < 1024; off <<= 1) {
        const unsigned int v = sc[t];
        const unsigned int add = (t >= off) ? sc[t - off] : 0u;
        __syncthreads();
        sc[t] = v + add;
        __syncthreads();
    }
    unsigned int base = sc[t] - mycnt;   // exclusive prefix, ascending n
    unsigned short* lc = lists + (size_t)c * Nn;
    unsigned int wrd = word;
    while (wrd) {
        const int j = __ffs(wrd) - 1;
        lc[base++] = (unsigned short)(r0 + j);
        wrd &= wrd - 1;
    }
    if (t == 1023) cnt[c] = sc[1023];
}

// ---- refine v4: 32-row slices -> 68 KB LDS -> 2 blocks/CU (latency fix) ----
// 256 thr = 32 kl x 8 rg; thread = 4 rows x 4 codes. fmaf chain ascending-d,
// bit-identical to the proven chain; dup-padded tails idempotent via atomicMin.
#define NGB 16
__global__ void __launch_bounds__(256, 2)
k_refine(const float* __restrict__ xT, const float* __restrict__ w,
         const float* __restrict__ sw2, const float* __restrict__ cn,
         const unsigned int* __restrict__ cnt, const unsigned short* __restrict__ lists,
         unsigned long long* __restrict__ keys) {
    __shared__ __align__(16) float xs[32 * 260];   // 33.3 KB
    __shared__ __align__(16) float ws[128 * 68];   // 34.8 KB
    __shared__ float cns[32];
    __shared__ unsigned short rid_s[32];
    const int c = blockIdx.x, gb = blockIdx.y;
    const int tid = threadIdx.x;
    const int cntc = (int)cnt[c];
    const int kl = tid & 31, rg = tid >> 5;   // rg 0..7
    float swk[4];
#pragma unroll
    for (int cc = 0; cc < 4; ++cc) swk[cc] = sw2[128 * c + kl + 32 * cc];

    for (int start = gb * 32; start < cntc; start += NGB * 32) {
        // stage 32 candidate rows (coalesced float4)
#pragma unroll
        for (int m = 0; m < 8; ++m) {
            const int e = tid + 256 * m;      // 0..2047
            const int j = e >> 6, d4 = e & 63;
            const int li = min(start + j, cntc - 1);
            const int row = lists[(size_t)c * Nn + li];
            *reinterpret_cast<float4*>(&xs[j * 260 + 4 * d4]) =
                *reinterpret_cast<const float4*>(&xT[(size_t)row * Dd + 4 * d4]);
        }
        if (tid < 32) {
            const int li = min(start + tid, cntc - 1);
            const unsigned short row = lists[(size_t)c * Nn + li];
            rid_s[tid] = row;
            cns[tid] = cn[row];
        }
        __syncthreads();

        float acc[4][4];
#pragma unroll
        for (int rr = 0; rr < 4; ++rr)
#pragma unroll
            for (int cc = 0; cc < 4; ++cc) acc[rr][cc] = 0.0f;

        for (int step = 0; step < 4; ++step) {
#pragma unroll
            for (int m = 0; m < 8; ++m) {
                const int e = tid + 256 * m;  // 0..2047
                const int code = e >> 4, dseg = e & 15;
                *reinterpret_cast<float4*>(&ws[code * 68 + 4 * dseg]) =
                    *reinterpret_cast<const float4*>(
                        &w[(size_t)(128 * c + code) * Dd + step * 64 + 4 * dseg]);
            }
            __syncthreads();
#pragma unroll
            for (int dl = 0; dl < 16; ++dl) {
                float4 wv[4];
#pragma unroll
                for (int cc = 0; cc < 4; ++cc)
                    wv[cc] = *reinterpret_cast<const float4*>(
                        &ws[(kl + 32 * cc) * 68 + 4 * dl]);
#pragma unroll
                for (int rr = 0; rr < 4; ++rr) {
                    const float4 xv = *reinterpret_cast<const float4*>(
                        &xs[(4 * rg + rr) * 260 + step * 64 + 4 * dl]);
#pragma unroll
                    for (int cc = 0; cc < 4; ++cc) {
                        acc[rr][cc] = fmaf(xv.x, wv[cc].x, acc[rr][cc]);
                        acc[rr][cc] = fmaf(xv.y, wv[cc].y, acc[rr][cc]);
                        acc[rr][cc] = fmaf(xv.z, wv[cc].z, acc[rr][cc]);
                        acc[rr][cc] = fmaf(xv.w, wv[cc].w, acc[rr][cc]);
                    }
                }
            }
            __syncthreads();
        }

        // per-row argmin: fold 4 codes in-thread, 32-lane shuffle reduce
#pragma unroll
        for (int rr = 0; rr < 4; ++rr) {
            const int rl = 4 * rg + rr;
            const float cr = cns[rl];
            float bv = 3.402823466e+38f;
            int bk = 0x7FFFFFFF;
#pragma unroll
            for (int cc = 0; cc < 4; ++cc) {
                const float t1 = cr + swk[cc];                // fl32(cn + sw)
                const float s = fmaf(-2.0f, acc[rr][cc], t1); // fl32(t1 - 2*dot)
                const int k = 128 * c + kl + 32 * cc;
                if (s < bv || (s == bv && k < bk)) { bv = s; bk = k; }
            }
#pragma unroll
            for (int d = 1; d < 32; d <<= 1) {
                const float ov = __shfl_xor(bv, d);
                const int ok = __shfl_xor(bk, d);
                if (ov < bv || (ov == bv && ok < bk)) { bv = ov; bk = ok; }
            }
            if (kl == 0) {
                const unsigned long long key =
                    ((unsigned long long)__float_as_uint(bv) << 32) |
                    (unsigned long long)(unsigned int)bk;
                atomicMin(&keys[rid_s[rl]], key);
            }
        }
        __syncthreads();
    }
}

// ---- gather + STE + partial loss (proven, key-indexed) ----
__global__ void k_quant2(const float* __restrict__ x, const float* __restrict__ w,
                         const unsigned long long* __restrict__ keys,
                         float* __restrict__ outq, float* __restrict__ idxf,
                         double* __restrict__ part) {
#pragma clang fp contract(off)
    __shared__ double red[256];
    const int tid = threadIdx.x;
    const int n0 = blockIdx.x * 64;
    const int b = n0 >> 10, t0 = n0 & 1023;
    const int tl = tid & 63;
    const int d0 = tid >> 6;
    const int n = n0 + tl;
    const int code = (int)(unsigned int)(keys[n] & 0xFFFFFFFFULL);
    if (tid < 64) idxf[n0 + tid] = (float)(int)(unsigned int)(keys[n0 + tid] & 0xFFFFFFFFULL);
    const float* wr = w + (size_t)code * Dd;
    const size_t base = (size_t)b * (Dd * Tt) + t0 + tl;
    double s = 0.0;
    for (int d = d0; d < Dd; d += 4) {
        const float xv = x[base + (size_t)d * Tt];
        const float qv = wr[d];
        const float d1 = qv - xv;
        const float qs = xv + d1;
        const float d2 = qs - xv;
        s += (double)d2 * (double)d2;
        outq[base + (size_t)d * Tt] = qs;
    }
    red[tid] = s;
    __syncthreads();
    for (int st = 128; st > 0; st >>= 1) {
        if (tid < st) red[tid] += red[tid + st];
        __syncthreads();
    }
    if (tid == 0) part[blockIdx.x] = red[0];
}

__global__ void k_loss(const double* __restrict__ part, float* __restrict__ loss) {
    __shared__ double red[512];
    const int tid = threadIdx.x;
    red[tid] = part[tid];
    __syncthreads();
    for (int st = 256; st > 0; st >>= 1) {
        if (tid < st) red[tid] += red[tid + st];
        __syncthreads();
    }
    if (tid == 0)
        loss[0] = (float)(1.25 * red[0] / (double)((size_t)Bn * Dd * Tt));
}

// ===================== LEGACY (round-2 proven) FALLBACK =====================
__global__ void k_transpose(const float* __restrict__ w, float* __restrict__ wtg) {
    __shared__ float tile[32][33];
    const int k0 = blockIdx.x * 32;
    const int d0 = blockIdx.y * 32;
    const int tx = threadIdx.x, ty = threadIdx.y;
#pragma unroll
    for (int r = 0; r < 32; r += 8)
        tile[r + ty][tx] = w[(size_t)(k0 + r + ty) * Dd + d0 + tx];
    __syncthreads();
#pragma unroll
    for (int r = 0; r < 32; r += 8)
        wtg[(size_t)(d0 + r + ty) * Kk + k0 + tx] = tile[tx][r + ty];
}

__global__ void k_sumx2_np_legacy(const float* __restrict__ x, float* __restrict__ c) {
#pragma clang fp contract(off)
    const int n = blockIdx.x * 256 + threadIdx.x;
    const int b = n >> 10, t = n & 1023;
    const float* p = x + (size_t)b * (Dd * Tt) + t;
    float h[2];
#pragma unroll
    for (int half = 0; half < 2; ++half) {
        float r[8];
#pragma unroll
        for (int j = 0; j < 8; ++j) {
            const float v = p[(size_t)(half * 128 + j) * Tt];
            r[j] = v * v;
        }
        for (int i = 8; i < 128; i += 8) {
#pragma unroll
            for (int j = 0; j < 8; ++j) {
                const float v = p[(size_t)(half * 128 + i + j) * Tt];
                const float sq = v * v;
                r[j] = r[j] + sq;
            }
        }
        h[half] = ((r[0] + r[1]) + (r[2] + r[3])) + ((r[4] + r[5]) + (r[6] + r[7]));
    }
    c[n] = h[0] + h[1];
}

template <bool WTG>
__global__ void __launch_bounds__(512, 2)
k_argmin(const float* __restrict__ x, const float* __restrict__ w,
         const float* __restrict__ wtg, const float* __restrict__ sw2,
         const float* __restrict__ cn,
         int* __restrict__ idx_out, float* __restrict__ idx_f) {
    __shared__ __align__(16) float At[32][132];
    __shared__ __align__(16) float Wt[32][268];
    const int tid = threadIdx.x;
    const int n0 = blockIdx.x * 128;
    const int b = n0 >> 10;
    const int t0 = n0 & 1023;
    const int ty = tid >> 5;
    const int tx = tid & 31;
    const int r0 = ty * 4;
    const int c0 = tx * 4;
    const float* xb = x + (size_t)b * (Dd * Tt) + t0;

    float c8[8];
#pragma unroll
    for (int i = 0; i < 8; ++i) {
        const int row = (i < 4) ? (r0 + i) : (64 + r0 + (i - 4));
        c8[i] = cn[n0 + row];
    }
    float best[8];
    int bidx[8];
#pragma unroll
    for (int i = 0; i < 8; ++i) { best[i] = 3.402823466e+38f; bidx[i] = 0; }

    for (int kc = 0; kc < Kk; kc += 256) {
        float acc[8][8];
#pragma unroll
        for (int i = 0; i < 8; ++i)
#pragma unroll
            for (int j = 0; j < 8; ++j) acc[i][j] = 0.0f;
        for (int ds = 0; ds < Dd; ds += 32) {
#pragma unroll
            for (int u = 0; u < 2; ++u) {
                int cc = tid + 512 * u;
                int dd = cc >> 5, i4 = cc & 31;
                float4 v = *reinterpret_cast<const float4*>(
                    &xb[(size_t)(ds + dd) * Tt + i4 * 4]);
                *reinterpret_cast<float4*>(&At[dd][i4 * 4]) = v;
            }
            if (WTG) {
#pragma unroll
                for (int u = 0; u < 4; ++u) {
                    int cc = tid + 512 * u;
                    int dd = cc >> 6, j4 = cc & 63;
                    float4 v = *reinterpret_cast<const float4*>(
                        &wtg[(size_t)(ds + dd) * Kk + kc + j4 * 4]);
                    *reinterpret_cast<float4*>(&Wt[dd][j4 * 4]) = v;
                }
            } else {
#pragma unroll
                for (int u = 0; u < 4; ++u) {
                    int cc = tid + 512 * u;
                    int j = cc >> 3, m = cc & 7;
                    float4 v = *reinterpret_cast<const float4*>(
                        &w[(size_t)(kc + j) * Dd + ds + m * 4]);
                    Wt[m * 4 + 0][j] = v.x;
                    Wt[m * 4 + 1][j] = v.y;
                    Wt[m * 4 + 2][j] = v.z;
                    Wt[m * 4 + 3][j] = v.w;
                }
            }
            __syncthreads();
#pragma unroll 8
            for (int dd = 0; dd < 32; ++dd) {
                float4 a0 = *reinterpret_cast<const float4*>(&At[dd][r0]);
                float4 a1 = *reinterpret_cast<const float4*>(&At[dd][64 + r0]);
                float4 b0 = *reinterpret_cast<const float4*>(&Wt[dd][c0]);
                float4 b1 = *reinterpret_cast<const float4*>(&Wt[dd][128 + c0]);
                float av[8] = {a0.x, a0.y, a0.z, a0.w, a1.x, a1.y, a1.z, a1.w};
                float bv[8] = {b0.x, b0.y, b0.z, b0.w, b1.x, b1.y, b1.z, b1.w};
#pragma unroll
                for (int i = 0; i < 8; ++i)
#pragma unroll
                    for (int j = 0; j < 8; ++j)
                        acc[i][j] = fmaf(av[i], bv[j], acc[i][j]);
            }
            __syncthreads();
        }
#pragma unroll
        for (int j = 0; j < 8; ++j) {
            const int col = (j < 4) ? (c0 + j) : (128 + c0 + (j - 4));
            const int k = kc + col;
            const float sw = sw2[k];
#pragma unroll
            for (int i = 0; i < 8; ++i) {
                const float t1 = c8[i] + sw;
                const float s = fmaf(-2.0f, acc[i][j], t1);
                if (s < best[i] || (s == best[i] && k < bidx[i])) {
                    best[i] = s; bidx[i] = k;
                }
            }
        }
    }
#pragma unroll
    for (int i = 0; i < 8; ++i) {
        float v = best[i];
        int id = bidx[i];
#pragma unroll
        for (int m = 1; m < 32; m <<= 1) {
            const float ov = __shfl_xor(v, m);
            const int oi = __shfl_xor(id, m);
            if (ov < v || (ov == v && oi < id)) { v = ov; id = oi; }
        }
        if (tx == 0) {
            const int row = (i < 4) ? (r0 + i) : (64 + r0 + (i - 4));
            const int n = n0 + row;
            idx_out[n] = id;
            idx_f[n] = (float)id;
        }
    }
}

__global__ void k_quant(const float* __restrict__ x, const float* __restrict__ w,
                        const int* __restrict__ idx, float* __restrict__ outq,
                        double* __restrict__ part) {
#pragma clang fp contract(off)
    __shared__ double red[256];
    const int tid = threadIdx.x;
    const int n0 = blockIdx.x * 64;
    const int b = n0 >> 10, t0 = n0 & 1023;
    const int tl = tid & 63;
    const int d0 = tid >> 6;
    const int n = n0 + tl;
    const int code = idx[n];
    const float* wr = w + (size_t)code * Dd;
    const size_t base = (size_t)b * (Dd * Tt) + t0 + tl;
    double s = 0.0;
    for (int d = d0; d < Dd; d += 4) {
        const float xv = x[base + (size_t)d * Tt];
        const float qv = wr[d];
        const float d1 = qv - xv;
        const float qs = xv + d1;
        const float d2 = qs - xv;
        s += (double)d2 * (double)d2;
        outq[base + (size_t)d * Tt] = qs;
    }
    red[tid] = s;
    __syncthreads();
    for (int st = 128; st > 0; st >>= 1) {
        if (tid < st) red[tid] += red[tid + st];
        __syncthreads();
    }
    if (tid == 0) part[blockIdx.x] = red[0];
}

// ===================== host =====================
extern "C" void kernel_launch(void* const* d_in, const int* in_sizes, int n_in,
                              void* d_out, int out_size, void* d_ws, size_t ws_size,
                              hipStream_t stream) {
    const float* x = (const float*)d_in[0];
    const float* w = (const float*)d_in[1];
    float* out = (float*)d_out;
    float* loss = out;
    float* outq = out + 1;
    float* idxf = out + 1 + (size_t)Bn * Dd * Tt;
    char* ws = (char*)d_ws;

    if (ws_size >= WS_NEED) {
        float* xT = (float*)(ws + OFF_XT);
        short* xbt = (short*)(ws + OFF_XBT);
        short* wbt = (short*)(ws + OFF_WBT);
        float* cm = (float*)(ws + OFF_CM);
        unsigned long long* mask = (unsigned long long*)(ws + OFF_MASK); // aliases dead xbt
        unsigned short* lists = (unsigned short*)(ws + OFF_LIST);
        unsigned long long* keys = (unsigned long long*)(ws + OFF_KEYS);
        float* sw2 = (float*)(ws + OFF_SW2);
        float* cn = (float*)(ws + OFF_CN);
        unsigned int* cnt = (unsigned int*)(ws + OFF_CNT);
        double* part = (double*)(ws + OFF_PART);

        k_xprep<<<dim3(32, 8, 32), dim3(32, 8), 0, stream>>>(x, xT, xbt);
        k_wbf_frag<<<(Kk * Dd / 8) / 256, 256, 0, stream>>>(w, wbt);
        k_sumx2_np<<<Nn / 128, 128, 0, stream>>>(x, cn);
        k_sumw2_np<<<Kk / 256, 256, 0, stream>>>(w, sw2);
        k_mfma_filter<<<dim3(Nn / 128, 2), 512, 0, stream>>>(xbt, wbt, sw2, cm);
        k_mask<<<Nn / 256, 256, 0, stream>>>(cm, cn, mask, keys);
        k_compact<<<64, 1024, 0, stream>>>(mask, cnt, lists);
        k_refine<<<dim3(64, NGB), 256, 0, stream>>>(xT, w, sw2, cn, cnt, lists, keys);
        k_quant2<<<Nn / 64, 256, 0, stream>>>(x, w, keys, outq, idxf, part);
        k_loss<<<1, 512, 0, stream>>>(part, loss);
    } else {
        // legacy round-2 path
        float* sw2 = (float*)(ws);
        int* idx = (int*)(ws + 32768);
        double* part = (double*)(ws + 163840);
        float* cn = (float*)(ws + 172032);
        float* wtg = (float*)(ws + 524288);
        const bool use_wtg = ws_size >= (size_t)524288 + (size_t)Kk * Dd * 4;
        if (use_wtg)
            k_transpose<<<dim3(Kk / 32, Dd / 32), dim3(32, 8), 0, stream>>>(w, wtg);
        k_sumx2_np_legacy<<<Nn / 256, 256, 0, stream>>>(x, cn);
        k_sumw2_np<<<Kk / 256, 256, 0, stream>>>(w, sw2);
        if (use_wtg)
            k_argmin<true><<<Nn / 128, 512, 0, stream>>>(x, w, wtg, sw2, cn, idx, idxf);
        else
            k_argmin<false><<<Nn / 128, 512, 0, stream>>>(x, w, wtg, sw2, cn, idx, idxf);
        k_quant<<<Nn / 64, 256, 0, stream>>>(x, w, idx, outq, part);
        k_loss<<<1, 512, 0, stream>>>(part, loss);
    }
}

// Round 18
// 404.444 us; speedup vs baseline: 1.1849x; 1.0098x over previous
//
#include <hip/hip_runtime.h>
#include <hip/hip_bf16.h>

#define Bn 32
#define Dd 256
#define Tt 1024
#define Nn (Bn * Tt)   // 32768
#define Kk 8192

typedef __attribute__((ext_vector_type(8))) short bf16x8;
typedef __attribute__((ext_vector_type(4))) float f32x4;

static __device__ __forceinline__ short f2bf(float v) {
    __hip_bfloat16 h = __float2bfloat16(v);
    return *reinterpret_cast<short*>(&h);
}

// ===================== ws layout (total == proven 75927808) ====================
#define OFF_XT    0ULL            // f32 [32768][256]  32 MB
#define OFF_XBT   33554432ULL     // bf16 [32768][256] 16 MB (dead after filter -> mask reuses)
#define OFF_WBT   50331648ULL     // bf16 fragment-ordered [64 chunks][4096 units][8]  4 MB
#define OFF_CM    54525952ULL     // f32 [32768][128]  16 MB  (chunk-min, col=2c+cp)
#define OFF_LIST  71303168ULL     // u16 [64][32768]    4 MB
#define OFF_KEYS  75497472ULL     // u64 [32768]      256 KB
#define OFF_SW2   75759616ULL     // f32 [8192]
#define OFF_CN    75792384ULL     // f32 [32768]
#define OFF_CNT   75923456ULL     // u32 [64]
#define OFF_PART  75923712ULL     // f64 [512]
#define WS_NEED   75927808ULL
#define OFF_MASK  OFF_XBT         // u64 [32768] 256 KB, aliases dead xbt

// ---- prep: x [b][d][t] -> xT f32 [n][d], xbt bf16 [n][d] ----
__global__ void k_xprep(const float* __restrict__ x, float* __restrict__ xT,
                        short* __restrict__ xbt) {
    __shared__ float tile[32][33];
    const int b = blockIdx.z, d0 = blockIdx.y * 32, t0 = blockIdx.x * 32;
    const int tx = threadIdx.x, ty = threadIdx.y;
#pragma unroll
    for (int r = 0; r < 32; r += 8)
        tile[ty + r][tx] = x[((size_t)(b * Dd + d0 + ty + r)) * Tt + t0 + tx];
    __syncthreads();
#pragma unroll
    for (int r = 0; r < 32; r += 8) {
        const size_t o = (size_t)(b * Tt + t0 + ty + r) * Dd + d0 + tx;
        const float v = tile[tx][ty + r];
        xT[o] = v;
        xbt[o] = f2bf(v);
    }
}

// ---- prep: w -> bf16 in FRAGMENT ORDER (round-16 proven) ----
__global__ void k_wbf_frag(const float* __restrict__ w, short* __restrict__ wf) {
    const int u = blockIdx.x * 256 + threadIdx.x;   // 0..262143
    const int c = u >> 12, e = u & 4095;
    const int g = e >> 9, ks = (e >> 6) & 7, fl4 = (e >> 4) & 3, fl15 = e & 15;
    const float* src = &w[(size_t)(128 * c + 16 * g + fl15) * Dd + ks * 32 + fl4 * 8];
    const float4 v0 = *reinterpret_cast<const float4*>(src);
    const float4 v1 = *reinterpret_cast<const float4*>(src + 4);
    short o[8];
    o[0] = f2bf(v0.x); o[1] = f2bf(v0.y); o[2] = f2bf(v0.z); o[3] = f2bf(v0.w);
    o[4] = f2bf(v1.x); o[5] = f2bf(v1.y); o[6] = f2bf(v1.z); o[7] = f2bf(v1.w);
    *reinterpret_cast<bf16x8*>(&wf[(size_t)u * 8]) = *reinterpret_cast<const bf16x8*>(o);
}

// ---- numpy-pairwise-exact sum of squares (proven round 2; round-9 grid) ----
__global__ void k_sumx2_np(const float* __restrict__ x, float* __restrict__ c) {
#pragma clang fp contract(off)
    const int n = blockIdx.x * 128 + threadIdx.x;
    const int b = n >> 10, t = n & 1023;
    const float* p = x + (size_t)b * (Dd * Tt) + t;
    float h[2];
#pragma unroll
    for (int half = 0; half < 2; ++half) {
        float r[8];
#pragma unroll
        for (int j = 0; j < 8; ++j) {
            const float v = p[(size_t)(half * 128 + j) * Tt];
            r[j] = v * v;
        }
        for (int i = 8; i < 128; i += 8) {
#pragma unroll
            for (int j = 0; j < 8; ++j) {
                const float v = p[(size_t)(half * 128 + i + j) * Tt];
                const float sq = v * v;
                r[j] = r[j] + sq;
            }
        }
        h[half] = ((r[0] + r[1]) + (r[2] + r[3])) + ((r[4] + r[5]) + (r[6] + r[7]));
    }
    c[n] = h[0] + h[1];
}

__global__ void k_sumw2_np(const float* __restrict__ w, float* __restrict__ sw) {
#pragma clang fp contract(off)
    const int k = blockIdx.x * 256 + threadIdx.x;
    const float* p = w + (size_t)k * Dd;
    float h[2];
#pragma unroll
    for (int half = 0; half < 2; ++half) {
        float r[8];
#pragma unroll
        for (int j = 0; j < 8; ++j) {
            const float v = p[half * 128 + j];
            r[j] = v * v;
        }
        for (int i = 8; i < 128; i += 8) {
#pragma unroll
            for (int j = 0; j < 8; ++j) {
                const float v = p[half * 128 + i + j];
                const float sq = v * v;
                r[j] = r[j] + sq;
            }
        }
        h[half] = ((r[0] + r[1]) + (r[2] + r[3])) + ((r[4] + r[5]) + (r[6] + r[7]));
    }
    sw[k] = h[0] + h[1];
}

// ---- stage 1: bf16 MFMA filter v7 (round-16/17 proven: 0 conflicts) ----
__global__ void __launch_bounds__(512, 4)
k_mfma_filter(const short* __restrict__ xbt, const short* __restrict__ wbt,
              const float* __restrict__ sw2, float* __restrict__ cm) {
    __shared__ __align__(16) short Wf[32768];   // 64 KB, fragment-ordered
    const int tid = threadIdx.x;
    const int n0 = blockIdx.x * 128;
    const int cbase = blockIdx.y * 32;
    const int wid = tid >> 6, lane = tid & 63;
    const int rp = wid >> 1, cp = wid & 1;
    const int l15 = lane & 15, l4 = lane >> 4;

    bf16x8 a[2][8];
#pragma unroll
    for (int rt = 0; rt < 2; ++rt)
#pragma unroll
        for (int ks = 0; ks < 8; ++ks)
            a[rt][ks] = *reinterpret_cast<const bf16x8*>(
                &xbt[(size_t)(n0 + 32 * rp + 16 * rt + l15) * Dd + 32 * ks + 8 * l4]);

    for (int cc = 0; cc < 32; ++cc) {
        const int c = cbase + cc;
        const short* wc = wbt + (size_t)c * 32768;   // chunk base (4096 units)
#pragma unroll
        for (int m = 0; m < 8; ++m) {
            const int e = tid + 512 * m;             // linear: global AND LDS
            *reinterpret_cast<bf16x8*>(&Wf[e * 8]) =
                *reinterpret_cast<const bf16x8*>(&wc[(size_t)e * 8]);
        }
        __syncthreads();

        f32x4 acc[2][4];
#pragma unroll
        for (int rt = 0; rt < 2; ++rt)
#pragma unroll
            for (int ct = 0; ct < 4; ++ct) acc[rt][ct] = (f32x4)0.0f;

#pragma unroll
        for (int ks = 0; ks < 8; ++ks) {
            bf16x8 b[4];
#pragma unroll
            for (int ct = 0; ct < 4; ++ct)
                b[ct] = *reinterpret_cast<const bf16x8*>(
                    &Wf[(((4 * cp + ct) * 8 + ks) * 64 + lane) * 8]);
#pragma unroll
            for (int rt = 0; rt < 2; ++rt)
#pragma unroll
                for (int ct = 0; ct < 4; ++ct)
                    acc[rt][ct] = __builtin_amdgcn_mfma_f32_16x16x32_bf16(
                        a[rt][ks], b[ct], acc[rt][ct], 0, 0, 0);
        }
        __syncthreads();   // Wf reads done; next iteration may restage

        float swc[4];
#pragma unroll
        for (int ct = 0; ct < 4; ++ct)
            swc[ct] = sw2[128 * c + 64 * cp + 16 * ct + l15];
#pragma unroll
        for (int rt = 0; rt < 2; ++rt) {
#pragma unroll
            for (int r = 0; r < 4; ++r) {
                float mm = fmaf(-2.0f, acc[rt][0][r], swc[0]);
#pragma unroll
                for (int ct = 1; ct < 4; ++ct)
                    mm = fminf(mm, fmaf(-2.0f, acc[rt][ct][r], swc[ct]));
#pragma unroll
                for (int d = 1; d < 16; d <<= 1)
                    mm = fminf(mm, __shfl_xor(mm, d));
                if (l15 == 0) {
                    const int row = n0 + 32 * rp + 16 * rt + 4 * l4 + r;
                    cm[(size_t)row * 128 + 2 * c + cp] = mm;   // [n][128], race-free
                }
            }
        }
    }
}

// ---- mask: per-row chunk mask over 128 cm columns (round-8 proven) ----
__global__ void __launch_bounds__(256)
k_mask(const float* __restrict__ cm, const float* __restrict__ cn,
       unsigned long long* __restrict__ mask, unsigned long long* __restrict__ keys) {
    const int tid = threadIdx.x;
    const int lane = tid & 63, w = tid >> 6;
    const int grp = lane >> 4, sub = lane & 15;
    const int n0 = blockIdx.x * 256;
    for (int pass = 0; pass < 16; ++pass) {
        const int row = n0 + pass * 16 + 4 * w + grp;
        const float4 v0 = *reinterpret_cast<const float4*>(&cm[(size_t)row * 128 + 8 * sub]);
        const float4 v1 = *reinterpret_cast<const float4*>(&cm[(size_t)row * 128 + 8 * sub + 4]);
        float gmin = fminf(fminf(fminf(v0.x, v0.y), fminf(v0.z, v0.w)),
                           fminf(fminf(v1.x, v1.y), fminf(v1.z, v1.w)));
#pragma unroll
        for (int m = 1; m < 16; m <<= 1) gmin = fminf(gmin, __shfl_xor(gmin, m));
        const float margin = 7.1e-5f + 2.6e-5f * sqrtf(cn[row]);
        const float thr = gmin + margin;
        unsigned int nib = 0;
        if (fminf(v0.x, v0.y) <= thr) nib |= 1u;
        if (fminf(v0.z, v0.w) <= thr) nib |= 2u;
        if (fminf(v1.x, v1.y) <= thr) nib |= 4u;
        if (fminf(v1.z, v1.w) <= thr) nib |= 8u;
        unsigned long long mk = (unsigned long long)nib << (4 * sub);
#pragma unroll
        for (int m = 1; m < 16; m <<= 1) mk |= __shfl_xor(mk, m);
        if (sub == 0) {
            mask[row] = mk;
            keys[row] = 0xFFFFFFFFFFFFFFFFULL;
        }
    }
}

// ---- compact: per-chunk candidate list via block prefix sum (proven round 7) ----
__global__ void __launch_bounds__(1024)
k_compact(const unsigned long long* __restrict__ mask,
          unsigned int* __restrict__ cnt, unsigned short* __restrict__ lists) {
    __shared__ unsigned int sc[1024];
    const int c = blockIdx.x;
    const int t = threadIdx.x;
    const int r0 = t * 32;
    unsigned int word = 0;
#pragma unroll
    for (int j = 0; j < 32; ++j)
        word |= (unsigned int)((mask[r0 + j] >> c) & 1ULL) << j;
    const unsigned int mycnt = __popc(word);
    sc[t] = mycnt;
    __syncthreads();
    for (int off = 1; off < 1024; off <<= 1) {
        const unsigned int v = sc[t];
        const unsigned int add = (t >= off) ? sc[t - off] : 0u;
        __syncthreads();
        sc[t] = v + add;
        __syncthreads();
    }
    unsigned int base = sc[t] - mycnt;   // exclusive prefix, ascending n
    unsigned short* lc = lists + (size_t)c * Nn;
    unsigned int wrd = word;
    while (wrd) {
        const int j = __ffs(wrd) - 1;
        lc[base++] = (unsigned short)(r0 + j);
        wrd &= wrd - 1;
    }
    if (t == 1023) cnt[c] = sc[1023];
}

// ---- refine v5: 32-row slices + 8-step [128][36] w-stage -> 51.3 KB LDS
// -> 3 blocks/CU. d still ascends 0..255 per (row,code): chain bit-identical.
#define NGB 16
__global__ void __launch_bounds__(256, 3)
k_refine(const float* __restrict__ xT, const float* __restrict__ w,
         const float* __restrict__ sw2, const float* __restrict__ cn,
         const unsigned int* __restrict__ cnt, const unsigned short* __restrict__ lists,
         unsigned long long* __restrict__ keys) {
    __shared__ __align__(16) float xs[32 * 260];   // 33.3 KB
    __shared__ __align__(16) float ws[128 * 36];   // 18.0 KB
    __shared__ float cns[32];
    __shared__ unsigned short rid_s[32];
    const int c = blockIdx.x, gb = blockIdx.y;
    const int tid = threadIdx.x;
    const int cntc = (int)cnt[c];
    const int kl = tid & 31, rg = tid >> 5;   // rg 0..7
    float swk[4];
#pragma unroll
    for (int cc = 0; cc < 4; ++cc) swk[cc] = sw2[128 * c + kl + 32 * cc];

    for (int start = gb * 32; start < cntc; start += NGB * 32) {
        // stage 32 candidate rows (coalesced float4)
#pragma unroll
        for (int m = 0; m < 8; ++m) {
            const int e = tid + 256 * m;      // 0..2047
            const int j = e >> 6, d4 = e & 63;
            const int li = min(start + j, cntc - 1);
            const int row = lists[(size_t)c * Nn + li];
            *reinterpret_cast<float4*>(&xs[j * 260 + 4 * d4]) =
                *reinterpret_cast<const float4*>(&xT[(size_t)row * Dd + 4 * d4]);
        }
        if (tid < 32) {
            const int li = min(start + tid, cntc - 1);
            const unsigned short row = lists[(size_t)c * Nn + li];
            rid_s[tid] = row;
            cns[tid] = cn[row];
        }
        __syncthreads();

        float acc[4][4];
#pragma unroll
        for (int rr = 0; rr < 4; ++rr)
#pragma unroll
            for (int cc = 0; cc < 4; ++cc) acc[rr][cc] = 0.0f;

        for (int step = 0; step < 8; ++step) {
            // stage w d-slice: [128 codes][32 d] (1024 float4, 128-B segments)
#pragma unroll
            for (int m = 0; m < 4; ++m) {
                const int e = tid + 256 * m;  // 0..1023
                const int code = e >> 3, dq = e & 7;
                *reinterpret_cast<float4*>(&ws[code * 36 + 4 * dq]) =
                    *reinterpret_cast<const float4*>(
                        &w[(size_t)(128 * c + code) * Dd + step * 32 + 4 * dq]);
            }
            __syncthreads();
#pragma unroll
            for (int dl = 0; dl < 8; ++dl) {
                float4 wv[4];
#pragma unroll
                for (int cc = 0; cc < 4; ++cc)
                    wv[cc] = *reinterpret_cast<const float4*>(
                        &ws[(kl + 32 * cc) * 36 + 4 * dl]);
#pragma unroll
                for (int rr = 0; rr < 4; ++rr) {
                    const float4 xv = *reinterpret_cast<const float4*>(
                        &xs[(4 * rg + rr) * 260 + step * 32 + 4 * dl]);
#pragma unroll
                    for (int cc = 0; cc < 4; ++cc) {
                        acc[rr][cc] = fmaf(xv.x, wv[cc].x, acc[rr][cc]);
                        acc[rr][cc] = fmaf(xv.y, wv[cc].y, acc[rr][cc]);
                        acc[rr][cc] = fmaf(xv.z, wv[cc].z, acc[rr][cc]);
                        acc[rr][cc] = fmaf(xv.w, wv[cc].w, acc[rr][cc]);
                    }
                }
            }
            __syncthreads();
        }

        // per-row argmin: fold 4 codes in-thread, 32-lane shuffle reduce
#pragma unroll
        for (int rr = 0; rr < 4; ++rr) {
            const int rl = 4 * rg + rr;
            const float cr = cns[rl];
            float bv = 3.402823466e+38f;
            int bk = 0x7FFFFFFF;
#pragma unroll
            for (int cc = 0; cc < 4; ++cc) {
                const float t1 = cr + swk[cc];                // fl32(cn + sw)
                const float s = fmaf(-2.0f, acc[rr][cc], t1); // fl32(t1 - 2*dot)
                const int k = 128 * c + kl + 32 * cc;
                if (s < bv || (s == bv && k < bk)) { bv = s; bk = k; }
            }
#pragma unroll
            for (int d = 1; d < 32; d <<= 1) {
                const float ov = __shfl_xor(bv, d);
                const int ok = __shfl_xor(bk, d);
                if (ov < bv || (ov == bv && ok < bk)) { bv = ov; bk = ok; }
            }
            if (kl == 0) {
                const unsigned long long key =
                    ((unsigned long long)__float_as_uint(bv) << 32) |
                    (unsigned long long)(unsigned int)bk;
                atomicMin(&keys[rid_s[rl]], key);
            }
        }
        __syncthreads();
    }
}

// ---- gather + STE + partial loss (proven, key-indexed) ----
__global__ void k_quant2(const float* __restrict__ x, const float* __restrict__ w,
                         const unsigned long long* __restrict__ keys,
                         float* __restrict__ outq, float* __restrict__ idxf,
                         double* __restrict__ part) {
#pragma clang fp contract(off)
    __shared__ double red[256];
    const int tid = threadIdx.x;
    const int n0 = blockIdx.x * 64;
    const int b = n0 >> 10, t0 = n0 & 1023;
    const int tl = tid & 63;
    const int d0 = tid >> 6;
    const int n = n0 + tl;
    const int code = (int)(unsigned int)(keys[n] & 0xFFFFFFFFULL);
    if (tid < 64) idxf[n0 + tid] = (float)(int)(unsigned int)(keys[n0 + tid] & 0xFFFFFFFFULL);
    const float* wr = w + (size_t)code * Dd;
    const size_t base = (size_t)b * (Dd * Tt) + t0 + tl;
    double s = 0.0;
    for (int d = d0; d < Dd; d += 4) {
        const float xv = x[base + (size_t)d * Tt];
        const float qv = wr[d];
        const float d1 = qv - xv;
        const float qs = xv + d1;
        const float d2 = qs - xv;
        s += (double)d2 * (double)d2;
        outq[base + (size_t)d * Tt] = qs;
    }
    red[tid] = s;
    __syncthreads();
    for (int st = 128; st > 0; st >>= 1) {
        if (tid < st) red[tid] += red[tid + st];
        __syncthreads();
    }
    if (tid == 0) part[blockIdx.x] = red[0];
}

__global__ void k_loss(const double* __restrict__ part, float* __restrict__ loss) {
    __shared__ double red[512];
    const int tid = threadIdx.x;
    red[tid] = part[tid];
    __syncthreads();
    for (int st = 256; st > 0; st >>= 1) {
        if (tid < st) red[tid] += red[tid + st];
        __syncthreads();
    }
    if (tid == 0)
        loss[0] = (float)(1.25 * red[0] / (double)((size_t)Bn * Dd * Tt));
}

// ===================== LEGACY (round-2 proven) FALLBACK =====================
__global__ void k_transpose(const float* __restrict__ w, float* __restrict__ wtg) {
    __shared__ float tile[32][33];
    const int k0 = blockIdx.x * 32;
    const int d0 = blockIdx.y * 32;
    const int tx = threadIdx.x, ty = threadIdx.y;
#pragma unroll
    for (int r = 0; r < 32; r += 8)
        tile[r + ty][tx] = w[(size_t)(k0 + r + ty) * Dd + d0 + tx];
    __syncthreads();
#pragma unroll
    for (int r = 0; r < 32; r += 8)
        wtg[(size_t)(d0 + r + ty) * Kk + k0 + tx] = tile[tx][r + ty];
}

__global__ void k_sumx2_np_legacy(const float* __restrict__ x, float* __restrict__ c) {
#pragma clang fp contract(off)
    const int n = blockIdx.x * 256 + threadIdx.x;
    const int b = n >> 10, t = n & 1023;
    const float* p = x + (size_t)b * (Dd * Tt) + t;
    float h[2];
#pragma unroll
    for (int half = 0; half < 2; ++half) {
        float r[8];
#pragma unroll
        for (int j = 0; j < 8; ++j) {
            const float v = p[(size_t)(half * 128 + j) * Tt];
            r[j] = v * v;
        }
        for (int i = 8; i < 128; i += 8) {
#pragma unroll
            for (int j = 0; j < 8; ++j) {
                const float v = p[(size_t)(half * 128 + i + j) * Tt];
                const float sq = v * v;
                r[j] = r[j] + sq;
            }
        }
        h[half] = ((r[0] + r[1]) + (r[2] + r[3])) + ((r[4] + r[5]) + (r[6] + r[7]));
    }
    c[n] = h[0] + h[1];
}

template <bool WTG>
__global__ void __launch_bounds__(512, 2)
k_argmin(const float* __restrict__ x, const float* __restrict__ w,
         const float* __restrict__ wtg, const float* __restrict__ sw2,
         const float* __restrict__ cn,
         int* __restrict__ idx_out, float* __restrict__ idx_f) {
    __shared__ __align__(16) float At[32][132];
    __shared__ __align__(16) float Wt[32][268];
    const int tid = threadIdx.x;
    const int n0 = blockIdx.x * 128;
    const int b = n0 >> 10;
    const int t0 = n0 & 1023;
    const int ty = tid >> 5;
    const int tx = tid & 31;
    const int r0 = ty * 4;
    const int c0 = tx * 4;
    const float* xb = x + (size_t)b * (Dd * Tt) + t0;

    float c8[8];
#pragma unroll
    for (int i = 0; i < 8; ++i) {
        const int row = (i < 4) ? (r0 + i) : (64 + r0 + (i - 4));
        c8[i] = cn[n0 + row];
    }
    float best[8];
    int bidx[8];
#pragma unroll
    for (int i = 0; i < 8; ++i) { best[i] = 3.402823466e+38f; bidx[i] = 0; }

    for (int kc = 0; kc < Kk; kc += 256) {
        float acc[8][8];
#pragma unroll
        for (int i = 0; i < 8; ++i)
#pragma unroll
            for (int j = 0; j < 8; ++j) acc[i][j] = 0.0f;
        for (int ds = 0; ds < Dd; ds += 32) {
#pragma unroll
            for (int u = 0; u < 2; ++u) {
                int cc = tid + 512 * u;
                int dd = cc >> 5, i4 = cc & 31;
                float4 v = *reinterpret_cast<const float4*>(
                    &xb[(size_t)(ds + dd) * Tt + i4 * 4]);
                *reinterpret_cast<float4*>(&At[dd][i4 * 4]) = v;
            }
            if (WTG) {
#pragma unroll
                for (int u = 0; u < 4; ++u) {
                    int cc = tid + 512 * u;
                    int dd = cc >> 6, j4 = cc & 63;
                    float4 v = *reinterpret_cast<const float4*>(
                        &wtg[(size_t)(ds + dd) * Kk + kc + j4 * 4]);
                    *reinterpret_cast<float4*>(&Wt[dd][j4 * 4]) = v;
                }
            } else {
#pragma unroll
                for (int u = 0; u < 4; ++u) {
                    int cc = tid + 512 * u;
                    int j = cc >> 3, m = cc & 7;
                    float4 v = *reinterpret_cast<const float4*>(
                        &w[(size_t)(kc + j) * Dd + ds + m * 4]);
                    Wt[m * 4 + 0][j] = v.x;
                    Wt[m * 4 + 1][j] = v.y;
                    Wt[m * 4 + 2][j] = v.z;
                    Wt[m * 4 + 3][j] = v.w;
                }
            }
            __syncthreads();
#pragma unroll 8
            for (int dd = 0; dd < 32; ++dd) {
                float4 a0 = *reinterpret_cast<const float4*>(&At[dd][r0]);
                float4 a1 = *reinterpret_cast<const float4*>(&At[dd][64 + r0]);
                float4 b0 = *reinterpret_cast<const float4*>(&Wt[dd][c0]);
                float4 b1 = *reinterpret_cast<const float4*>(&Wt[dd][128 + c0]);
                float av[8] = {a0.x, a0.y, a0.z, a0.w, a1.x, a1.y, a1.z, a1.w};
                float bv[8] = {b0.x, b0.y, b0.z, b0.w, b1.x, b1.y, b1.z, b1.w};
#pragma unroll
                for (int i = 0; i < 8; ++i)
#pragma unroll
                    for (int j = 0; j < 8; ++j)
                        acc[i][j] = fmaf(av[i], bv[j], acc[i][j]);
            }
            __syncthreads();
        }
#pragma unroll
        for (int j = 0; j < 8; ++j) {
            const int col = (j < 4) ? (c0 + j) : (128 + c0 + (j - 4));
            const int k = kc + col;
            const float sw = sw2[k];
#pragma unroll
            for (int i = 0; i < 8; ++i) {
                const float t1 = c8[i] + sw;
                const float s = fmaf(-2.0f, acc[i][j], t1);
                if (s < best[i] || (s == best[i] && k < bidx[i])) {
                    best[i] = s; bidx[i] = k;
                }
            }
        }
    }
#pragma unroll
    for (int i = 0; i < 8; ++i) {
        float v = best[i];
        int id = bidx[i];
#pragma unroll
        for (int m = 1; m < 32; m <<= 1) {
            const float ov = __shfl_xor(v, m);
            const int oi = __shfl_xor(id, m);
            if (ov < v || (ov == v && oi < id)) { v = ov; id = oi; }
        }
        if (tx == 0) {
            const int row = (i < 4) ? (r0 + i) : (64 + r0 + (i - 4));
            const int n = n0 + row;
            idx_out[n] = id;
            idx_f[n] = (float)id;
        }
    }
}

__global__ void k_quant(const float* __restrict__ x, const float* __restrict__ w,
                        const int* __restrict__ idx, float* __restrict__ outq,
                        double* __restrict__ part) {
#pragma clang fp contract(off)
    __shared__ double red[256];
    const int tid = threadIdx.x;
    const int n0 = blockIdx.x * 64;
    const int b = n0 >> 10, t0 = n0 & 1023;
    const int tl = tid & 63;
    const int d0 = tid >> 6;
    const int n = n0 + tl;
    const int code = idx[n];
    const float* wr = w + (size_t)code * Dd;
    const size_t base = (size_t)b * (Dd * Tt) + t0 + tl;
    double s = 0.0;
    for (int d = d0; d < Dd; d += 4) {
        const float xv = x[base + (size_t)d * Tt];
        const float qv = wr[d];
        const float d1 = qv - xv;
        const float qs = xv + d1;
        const float d2 = qs - xv;
        s += (double)d2 * (double)d2;
        outq[base + (size_t)d * Tt] = qs;
    }
    red[tid] = s;
    __syncthreads();
    for (int st = 128; st > 0; st >>= 1) {
        if (tid < st) red[tid] += red[tid + st];
        __syncthreads();
    }
    if (tid == 0) part[blockIdx.x] = red[0];
}

// ===================== host =====================
extern "C" void kernel_launch(void* const* d_in, const int* in_sizes, int n_in,
                              void* d_out, int out_size, void* d_ws, size_t ws_size,
                              hipStream_t stream) {
    const float* x = (const float*)d_in[0];
    const float* w = (const float*)d_in[1];
    float* out = (float*)d_out;
    float* loss = out;
    float* outq = out + 1;
    float* idxf = out + 1 + (size_t)Bn * Dd * Tt;
    char* ws = (char*)d_ws;

    if (ws_size >= WS_NEED) {
        float* xT = (float*)(ws + OFF_XT);
        short* xbt = (short*)(ws + OFF_XBT);
        short* wbt = (short*)(ws + OFF_WBT);
        float* cm = (float*)(ws + OFF_CM);
        unsigned long long* mask = (unsigned long long*)(ws + OFF_MASK); // aliases dead xbt
        unsigned short* lists = (unsigned short*)(ws + OFF_LIST);
        unsigned long long* keys = (unsigned long long*)(ws + OFF_KEYS);
        float* sw2 = (float*)(ws + OFF_SW2);
        float* cn = (float*)(ws + OFF_CN);
        unsigned int* cnt = (unsigned int*)(ws + OFF_CNT);
        double* part = (double*)(ws + OFF_PART);

        k_xprep<<<dim3(32, 8, 32), dim3(32, 8), 0, stream>>>(x, xT, xbt);
        k_wbf_frag<<<(Kk * Dd / 8) / 256, 256, 0, stream>>>(w, wbt);
        k_sumx2_np<<<Nn / 128, 128, 0, stream>>>(x, cn);
        k_sumw2_np<<<Kk / 256, 256, 0, stream>>>(w, sw2);
        k_mfma_filter<<<dim3(Nn / 128, 2), 512, 0, stream>>>(xbt, wbt, sw2, cm);
        k_mask<<<Nn / 256, 256, 0, stream>>>(cm, cn, mask, keys);
        k_compact<<<64, 1024, 0, stream>>>(mask, cnt, lists);
        k_refine<<<dim3(64, NGB), 256, 0, stream>>>(xT, w, sw2, cn, cnt, lists, keys);
        k_quant2<<<Nn / 64, 256, 0, stream>>>(x, w, keys, outq, idxf, part);
        k_loss<<<1, 512, 0, stream>>>(part, loss);
    } else {
        // legacy round-2 path
        float* sw2 = (float*)(ws);
        int* idx = (int*)(ws + 32768);
        double* part = (double*)(ws + 163840);
        float* cn = (float*)(ws + 172032);
        float* wtg = (float*)(ws + 524288);
        const bool use_wtg = ws_size >= (size_t)524288 + (size_t)Kk * Dd * 4;
        if (use_wtg)
            k_transpose<<<dim3(Kk / 32, Dd / 32), dim3(32, 8), 0, stream>>>(w, wtg);
        k_sumx2_np_legacy<<<Nn / 256, 256, 0, stream>>>(x, cn);
        k_sumw2_np<<<Kk / 256, 256, 0, stream>>>(w, sw2);
        if (use_wtg)
            k_argmin<true><<<Nn / 128, 512, 0, stream>>>(x, w, wtg, sw2, cn, idx, idxf);
        else
            k_argmin<false><<<Nn / 128, 512, 0, stream>>>(x, w, wtg, sw2, cn, idx, idxf);
        k_quant<<<Nn / 64, 256, 0, stream>>>(x, w, idx, outq, part);
        k_loss<<<1, 512, 0, stream>>>(part, loss);
    }
}